// Round 15
// baseline (266.690 us; speedup 1.0000x reference)
//
#include <hip/hip_runtime.h>

namespace {

constexpr int B = 4;
constexpr int N = 8192;          // power of two (N = 1<<13)
constexpr int E = 24576;
constexpr int BN = B * N;
constexpr int BE = B * E;
constexpr int GS = 32;           // grid cells per axis
constexpr int NC = GS * GS * GS; // 32768 cells per (set,b) grid
constexpr float LO = -4.2f;
constexpr float CS = 0.2625f;    // cell size (covers [-4.2, 4.2])
constexpr float INV = 1.0f / 0.2625f;

// Monotonic float <-> uint mapping (total order matches float compare)
__device__ __forceinline__ unsigned fkey(float f) {
  unsigned b = __float_as_uint(f);
  return b ^ ((b & 0x80000000u) ? 0xFFFFFFFFu : 0x80000000u);
}
__device__ __forceinline__ float funkey(unsigned k) {
  unsigned b = k ^ ((k & 0x80000000u) ? 0x80000000u : 0xFFFFFFFFu);
  return __uint_as_float(b);
}
__device__ __forceinline__ int clamp31(int v) { return v < 0 ? 0 : (v > 31 ? 31 : v); }

// sums layout (floats): [0]=s1, [1]=s2, [2]=cos sum, [3..14]=nsq[b][d],
// [15..26]=vsq[b][d], [30]=edgeB completion ticket (unsigned)

__global__ __launch_bounds__(256) void z0_kernel(uint4* __restrict__ cnt4,
                                                 float* __restrict__ sums) {
  int i = blockIdx.x * 256 + threadIdx.x;   // 65536 threads x uint4 = 1MB
  cnt4[i] = uint4{0u, 0u, 0u, 0u};
  if (i < 32) sums[i] = 0.f;
}

// A[i] = (-2*p, |p|^2), G[i] = (-2*g, |g|^2); cell ids + histograms.
__global__ __launch_bounds__(256) void prep2_kernel(const float* __restrict__ preds,
                                                    const float* __restrict__ gts,
                                                    float4* __restrict__ A,
                                                    float4* __restrict__ G,
                                                    unsigned* __restrict__ cellA,
                                                    unsigned* __restrict__ cellG,
                                                    unsigned* __restrict__ cnt) {
  int i = blockIdx.x * 256 + threadIdx.x;
  int b = i >> 13;
  float px = preds[3*i], py = preds[3*i+1], pz = preds[3*i+2];
  float gx = gts[3*i],   gy = gts[3*i+1],  gz = gts[3*i+2];
  A[i] = make_float4(-2.f*px, -2.f*py, -2.f*pz, px*px + py*py + pz*pz);
  G[i] = make_float4(-2.f*gx, -2.f*gy, -2.f*gz, gx*gx + gy*gy + gz*gz);
  int ax = clamp31((int)floorf((px - LO) * INV));
  int ay = clamp31((int)floorf((py - LO) * INV));
  int az = clamp31((int)floorf((pz - LO) * INV));
  unsigned ca = (unsigned)((az << 10) | (ay << 5) | ax);
  int bx_ = clamp31((int)floorf((gx - LO) * INV));
  int by_ = clamp31((int)floorf((gy - LO) * INV));
  int bz_ = clamp31((int)floorf((gz - LO) * INV));
  unsigned cg = (unsigned)((bz_ << 10) | (by_ << 5) | bx_);
  cellA[i] = ca; cellG[i] = cg;
  atomicAdd(&cnt[((unsigned)(0*4 + b) << 15) + ca], 1u);   // set0 = preds
  atomicAdd(&cnt[((unsigned)(1*4 + b) << 15) + cg], 1u);   // set1 = gts
}

// Exclusive scan per (set,b) grid: 8 blocks x 1024 threads, 32 cells/thread.
__global__ __launch_bounds__(1024) void scan_kernel(const unsigned* __restrict__ cnt,
                                                    unsigned* __restrict__ offs,
                                                    unsigned* __restrict__ fill) {
  __shared__ unsigned sd[1024];
  const unsigned base = (unsigned)blockIdx.x << 15;
  const int t = threadIdx.x;
  const unsigned cbase = base + (unsigned)t * 32u;
  unsigned s = 0;
  for (int j = 0; j < 32; ++j) s += cnt[cbase + j];
  sd[t] = s;
  __syncthreads();
  for (int off = 1; off < 1024; off <<= 1) {
    unsigned v = (t >= off) ? sd[t - off] : 0u;
    __syncthreads();
    sd[t] += v;
    __syncthreads();
  }
  unsigned run = (t == 0) ? 0u : sd[t - 1];
  for (int j = 0; j < 32; ++j) {
    unsigned c = cnt[cbase + j];
    offs[cbase + j] = run;
    fill[cbase + j] = run;
    run += c;
  }
}

// Counting-sort scatter (order within cell arbitrary; min is order-invariant).
__global__ __launch_bounds__(256) void scatter_kernel(const float4* __restrict__ A,
                                                      const float4* __restrict__ G,
                                                      const unsigned* __restrict__ cellA,
                                                      const unsigned* __restrict__ cellG,
                                                      unsigned* __restrict__ fill,
                                                      float4* __restrict__ sA,
                                                      unsigned* __restrict__ iA,
                                                      float4* __restrict__ sG,
                                                      unsigned* __restrict__ iG) {
  int i = blockIdx.x * 256 + threadIdx.x;
  int b = i >> 13;
  unsigned n = (unsigned)(i & (N - 1));
  unsigned ca = cellA[i];
  unsigned slot = atomicAdd(&fill[((unsigned)(0*4 + b) << 15) + ca], 1u);
  sA[(b << 13) + slot] = A[i]; iA[(b << 13) + slot] = n;
  unsigned cg = cellG[i];
  slot = atomicAdd(&fill[((unsigned)(1*4 + b) << 15) + cg], 1u);
  sG[(b << 13) + slot] = G[i]; iG[(b << 13) + slot] = n;
}

// Grid NN query. 4 lanes per query (stride-split candidates, shfl-merged).
//   t: sub = t&3, p = t>>2; which = p>>15 (0: queries=gts,db=preds -> m2;
//   1: queries=preds,db=gts -> m1). Queries processed in SORTED order so a
//   wave's lanes share cells (low divergence, coalesced db reads).
// Exactness: d uses the same fmaf chain as prior rounds; packed u64 min gives
// first-index tie semantics; ring bound (points in rings >R are >R*CS away,
// valid under clamping) guarantees the true argmin is visited before break.
__global__ __launch_bounds__(256) void query_kernel(const float4* __restrict__ sA,
                                                    const unsigned* __restrict__ iA,
                                                    const float4* __restrict__ sG,
                                                    const unsigned* __restrict__ iG,
                                                    const unsigned* __restrict__ offs,
                                                    const unsigned* __restrict__ cnt,
                                                    unsigned long long* __restrict__ m2,
                                                    unsigned* __restrict__ m1) {
  const int t = blockIdx.x * 256 + threadIdx.x;    // 262144 threads
  const int sub = t & 3;
  const int p = t >> 2;
  const int which = p >> 15;
  const int q = p & 32767;
  const int b = q >> 13, j = q & 8191;
  const float4* __restrict__ sq   = which ? sA : sG;
  const unsigned* __restrict__ sqi = which ? iA : iG;
  const float4* __restrict__ db   = which ? sG : sA;
  const unsigned* __restrict__ dbi = which ? iG : iA;
  const unsigned gb = ((unsigned)((which << 2) + b)) << 15;   // db grid base
  float4 qr = sq[(b << 13) + j];
  unsigned orig = sqi[(b << 13) + j];
  const float px = -0.5f * qr.x, py = -0.5f * qr.y, pz = -0.5f * qr.z, w = qr.w;
  const int cx = clamp31((int)floorf((px - LO) * INV));
  const int cy = clamp31((int)floorf((py - LO) * INV));
  const int cz = clamp31((int)floorf((pz - LO) * INV));
  const float4* __restrict__ dbb = db + (b << 13);
  const unsigned* __restrict__ dbib = dbi + (b << 13);
  unsigned long long best = ~0ULL;
  for (int R = 1; R <= 32; ++R) {
    const int x0 = cx - R < 0 ? 0 : cx - R, x1 = cx + R > 31 ? 31 : cx + R;
    const int y0 = cy - R < 0 ? 0 : cy - R, y1 = cy + R > 31 ? 31 : cy + R;
    const int z0 = cz - R < 0 ? 0 : cz - R, z1 = cz + R > 31 ? 31 : cz + R;
    for (int zz = z0; zz <= z1; ++zz) {
      for (int yy = y0; yy <= y1; ++yy) {
        const unsigned rowb = gb + (unsigned)((zz << 10) | (yy << 5));
        const int s = (int)offs[rowb + x0];
        const int e = (int)(offs[rowb + x1] + cnt[rowb + x1]);
        for (int k = s + sub; k < e; k += 4) {
          float4 c = dbb[k];
          float d = w + fmaf(px, c.x, fmaf(py, c.y, fmaf(pz, c.z, c.w)));
          unsigned long long key = ((unsigned long long)fkey(d) << 32) | dbib[k];
          best = key < best ? key : best;
        }
      }
    }
    unsigned long long o = __shfl_xor(best, 1, 64); best = o < best ? o : best;
    o = __shfl_xor(best, 2, 64); best = o < best ? o : best;
    float bd = funkey((unsigned)(best >> 32));
    float rr = (float)R * CS;
    if (bd <= rr * rr) break;     // all 4 lanes agree (merged best)
  }
  if (sub == 0) {
    if (which == 0) m2[(b << 13) + orig] = best;
    else            m1[(b << 13) + orig] = (unsigned)(best >> 32);
  }
}

// edgeA, 512 blocks (R14-proven):
//  blocks [0,384): edge gathers (argmin from m2 low bits), SoA store, 6 col-sums.
//  blocks [384,512): chamfer reduce of m1/m2 -> sums[0], sums[1].
__global__ __launch_bounds__(256) void edgeA_kernel(const float* __restrict__ preds,
                                                    const float* __restrict__ normals,
                                                    const int* __restrict__ edges,
                                                    const unsigned long long* __restrict__ m2,
                                                    const unsigned* __restrict__ m1,
                                                    float* __restrict__ ev,
                                                    float* __restrict__ sums) {
  __shared__ float ws[4][6];
  const int tid = threadIdx.x;
  const int wid = tid >> 6, lane = tid & 63;
  if (blockIdx.x < 384) {
    const int b = blockIdx.x / 96;
    const int e = (blockIdx.x % 96) * 256 + tid;
    int e0 = edges[2*e], e1 = edges[2*e+1];
    const float* pb = preds   + 3*(size_t)b*N;
    const float* nb = normals + 3*(size_t)b*N;
    float vx = pb[3*e0]   - pb[3*e1];
    float vy = pb[3*e0+1] - pb[3*e1+1];
    float vz = pb[3*e0+2] - pb[3*e1+2];
    unsigned ni = (unsigned)m2[b*N + e0];          // exact argmin from query
    float nx = nb[3*ni], ny = nb[3*ni+1], nz = nb[3*ni+2];
    const int be = b * E + e;
    ev[0*BE + be] = vx; ev[1*BE + be] = vy; ev[2*BE + be] = vz;
    ev[3*BE + be] = nx; ev[4*BE + be] = ny; ev[5*BE + be] = nz;
    float v[6] = {nx*nx, ny*ny, nz*nz, vx*vx, vy*vy, vz*vz};
#pragma unroll
    for (int k = 0; k < 6; ++k)
#pragma unroll
      for (int o = 32; o; o >>= 1) v[k] += __shfl_down(v[k], o, 64);
    if (lane == 0) {
#pragma unroll
      for (int k = 0; k < 6; ++k) ws[wid][k] = v[k];
    }
    __syncthreads();
    if (tid < 6) {
      const int k = tid;
      float s = ws[0][k] + ws[1][k] + ws[2][k] + ws[3][k];
      atomicAdd(&sums[(k < 3 ? 3 + k : 12 + k) + b*3], s);  // nsq: 3+b*3+d, vsq: 15+b*3+d
    }
  } else {
    int i = (blockIdx.x - 384) * 256 + tid;
    float d2 = funkey((unsigned)(m2[i] >> 32));
    float d1 = funkey(m1[i]);
#pragma unroll
    for (int o = 32; o; o >>= 1) { d2 += __shfl_down(d2, o, 64); d1 += __shfl_down(d1, o, 64); }
    if (lane == 0) { ws[wid][0] = d2; ws[wid][1] = d1; }
    __syncthreads();
    if (tid == 0) {
      atomicAdd(&sums[1], ws[0][0] + ws[1][0] + ws[2][0] + ws[3][0]);
      atomicAdd(&sums[0], ws[0][1] + ws[1][1] + ws[2][1] + ws[3][1]);
    }
  }
}

// edgeB, 384 blocks (R14-proven): cosine term + final via last-block ticket.
__global__ __launch_bounds__(256) void edgeB_kernel(const float* __restrict__ ev,
                                                    float* __restrict__ sums,
                                                    float* __restrict__ out) {
  __shared__ float ws[4];
  __shared__ bool amLast;
  const int tid = threadIdx.x;
  const int b = blockIdx.x / 96;
  const int e = (blockIdx.x % 96) * 256 + tid;
  const int be = b * E + e;
  float vx = ev[0*BE + be], vy = ev[1*BE + be], vz = ev[2*BE + be];
  float nx = ev[3*BE + be], ny = ev[4*BE + be], nz = ev[5*BE + be];
  float inn0 = 1.f / fmaxf(sqrtf(sums[3  + b*3 + 0]), 1e-12f);
  float inn1 = 1.f / fmaxf(sqrtf(sums[3  + b*3 + 1]), 1e-12f);
  float inn2 = 1.f / fmaxf(sqrtf(sums[3  + b*3 + 2]), 1e-12f);
  float inv0 = 1.f / fmaxf(sqrtf(sums[15 + b*3 + 0]), 1e-12f);
  float inv1 = 1.f / fmaxf(sqrtf(sums[15 + b*3 + 1]), 1e-12f);
  float inv2 = 1.f / fmaxf(sqrtf(sums[15 + b*3 + 2]), 1e-12f);
  float c = fabsf(nx*inn0*vx*inv0 + ny*inn1*vy*inv1 + nz*inn2*vz*inv2);
#pragma unroll
  for (int o = 32; o; o >>= 1) c += __shfl_down(c, o, 64);
  if ((tid & 63) == 0) ws[tid >> 6] = c;
  __syncthreads();
  if (tid == 0) {
    atomicAdd(&sums[2], ws[0] + ws[1] + ws[2] + ws[3]);
    __threadfence();
    unsigned old = atomicAdd((unsigned*)(sums + 30), 1u);
    amLast = (old == 383u);
  }
  __syncthreads();
  if (amLast && tid == 0) {
    float esum = 0.f;
#pragma unroll
    for (int i = 0; i < 12; ++i) esum += atomicAdd(&sums[15 + i], 0.f);
    float s0 = atomicAdd(&sums[0], 0.f), s1 = atomicAdd(&sums[1], 0.f);
    float s2 = atomicAdd(&sums[2], 0.f);
    float chamfer   = (s0 + s1) * (1.f / (float)BN);
    float edge_loss = esum * (1.f / (float)(B * E));
    float ncl       = s2 * (1.f / (float)(B * E));
    out[0] = 30000.f * chamfer + 240.f * edge_loss + 200000.f * ncl;
  }
}

} // namespace

extern "C" void kernel_launch(void* const* d_in, const int* in_sizes, int n_in,
                              void* d_out, int out_size, void* d_ws, size_t ws_size,
                              hipStream_t stream) {
  (void)in_sizes; (void)n_in; (void)out_size; (void)ws_size;
  const float* preds   = (const float*)d_in[0];
  const float* gts     = (const float*)d_in[1];
  const float* normals = (const float*)d_in[2];
  const int*   edges   = (const int*)d_in[3];
  char* ws = (char*)d_ws;
  // ws layout: A 512K | G 512K | cellA 128K | cellG 128K | cnt 1M | offs 1M |
  //            fill 1M | sA 512K | sG 512K | iA 128K | iG 128K | m2 256K |
  //            m1 128K | sums 4K.  ev (2.25M) OVERLAYS cnt/offs/fill (dead
  //            after query; edgeA writes ev only after query completes).
  float4*             A     = (float4*)(ws);
  float4*             G     = (float4*)(ws + 0x080000);
  unsigned*           cellA = (unsigned*)(ws + 0x100000);
  unsigned*           cellG = (unsigned*)(ws + 0x120000);
  unsigned*           cnt   = (unsigned*)(ws + 0x140000);
  unsigned*           offs  = (unsigned*)(ws + 0x240000);
  unsigned*           fill  = (unsigned*)(ws + 0x340000);
  float4*             sA    = (float4*)(ws + 0x440000);
  float4*             sG    = (float4*)(ws + 0x4C0000);
  unsigned*           iA    = (unsigned*)(ws + 0x540000);
  unsigned*           iG    = (unsigned*)(ws + 0x560000);
  unsigned long long* m2    = (unsigned long long*)(ws + 0x580000);
  unsigned*           m1    = (unsigned*)(ws + 0x5C0000);
  float*              sums  = (float*)(ws + 0x5E0000);
  float*              ev    = (float*)(ws + 0x140000);   // overlay
  float* out = (float*)d_out;

  z0_kernel<<<dim3(256), 256, 0, stream>>>((uint4*)cnt, sums);
  prep2_kernel<<<dim3(BN/256), 256, 0, stream>>>(preds, gts, A, G, cellA, cellG, cnt);
  scan_kernel<<<dim3(8), 1024, 0, stream>>>(cnt, offs, fill);
  scatter_kernel<<<dim3(BN/256), 256, 0, stream>>>(A, G, cellA, cellG, fill, sA, iA, sG, iG);
  query_kernel<<<dim3(1024), 256, 0, stream>>>(sA, iA, sG, iG, offs, cnt, m2, m1);
  edgeA_kernel<<<dim3(512), 256, 0, stream>>>(preds, normals, edges, m2, m1, ev, sums);
  edgeB_kernel<<<dim3(384), 256, 0, stream>>>(ev, sums, out);
}

// Round 16
// 174.648 us; speedup vs baseline: 1.5270x; 1.5270x over previous
//
#include <hip/hip_runtime.h>

namespace {

constexpr int B = 4;
constexpr int N = 8192;          // power of two (N = 1<<13)
constexpr int E = 24576;
constexpr int BN = B * N;
constexpr int BE = B * E;
constexpr float LO = -4.2f;
constexpr float CS = 0.2625f;    // cell size (covers [-4.2, 4.2], 32 cells/axis)
constexpr float INV = 1.0f / 0.2625f;

// Monotonic float <-> uint mapping (total order matches float compare)
__device__ __forceinline__ unsigned fkey(float f) {
  unsigned b = __float_as_uint(f);
  return b ^ ((b & 0x80000000u) ? 0xFFFFFFFFu : 0x80000000u);
}
__device__ __forceinline__ float funkey(unsigned k) {
  unsigned b = k ^ ((k & 0x80000000u) ? 0x80000000u : 0xFFFFFFFFu);
  return __uint_as_float(b);
}
__device__ __forceinline__ int clamp31(int v) { return v < 0 ? 0 : (v > 31 ? 31 : v); }

// sums layout (floats): [0]=s1, [1]=s2, [2]=cos sum, [3..14]=nsq[b][d],
// [15..26]=vsq[b][d], [28]=fallback count (unsigned), [30]=edgeB ticket (unsigned)

__global__ __launch_bounds__(256) void z0_kernel(uint4* __restrict__ cnt4,
                                                 float* __restrict__ sums) {
  int i = blockIdx.x * 256 + threadIdx.x;   // 65536 threads x uint4 = 1MB
  cnt4[i] = uint4{0u, 0u, 0u, 0u};
  if (i < 32) sums[i] = 0.f;                // zeroes [28] and [30] too
}

// A[i] = (-2*p, |p|^2), G[i] = (-2*g, |g|^2); cell ids + histograms.
__global__ __launch_bounds__(256) void prep2_kernel(const float* __restrict__ preds,
                                                    const float* __restrict__ gts,
                                                    float4* __restrict__ A,
                                                    float4* __restrict__ G,
                                                    unsigned* __restrict__ cellA,
                                                    unsigned* __restrict__ cellG,
                                                    unsigned* __restrict__ cnt) {
  int i = blockIdx.x * 256 + threadIdx.x;
  int b = i >> 13;
  float px = preds[3*i], py = preds[3*i+1], pz = preds[3*i+2];
  float gx = gts[3*i],   gy = gts[3*i+1],  gz = gts[3*i+2];
  A[i] = make_float4(-2.f*px, -2.f*py, -2.f*pz, px*px + py*py + pz*pz);
  G[i] = make_float4(-2.f*gx, -2.f*gy, -2.f*gz, gx*gx + gy*gy + gz*gz);
  int ax = clamp31((int)floorf((px - LO) * INV));
  int ay = clamp31((int)floorf((py - LO) * INV));
  int az = clamp31((int)floorf((pz - LO) * INV));
  unsigned ca = (unsigned)((az << 10) | (ay << 5) | ax);
  int bx_ = clamp31((int)floorf((gx - LO) * INV));
  int by_ = clamp31((int)floorf((gy - LO) * INV));
  int bz_ = clamp31((int)floorf((gz - LO) * INV));
  unsigned cg = (unsigned)((bz_ << 10) | (by_ << 5) | bx_);
  cellA[i] = ca; cellG[i] = cg;
  atomicAdd(&cnt[((unsigned)(0*4 + b) << 15) + ca], 1u);   // set0 = preds
  atomicAdd(&cnt[((unsigned)(1*4 + b) << 15) + cg], 1u);   // set1 = gts
}

// Exclusive scan per (set,b) grid: 8 blocks x 1024 threads, 32 cells/thread.
__global__ __launch_bounds__(1024) void scan_kernel(const unsigned* __restrict__ cnt,
                                                    unsigned* __restrict__ offs,
                                                    unsigned* __restrict__ fill) {
  __shared__ unsigned sd[1024];
  const unsigned base = (unsigned)blockIdx.x << 15;
  const int t = threadIdx.x;
  const unsigned cbase = base + (unsigned)t * 32u;
  unsigned s = 0;
  for (int j = 0; j < 32; ++j) s += cnt[cbase + j];
  sd[t] = s;
  __syncthreads();
  for (int off = 1; off < 1024; off <<= 1) {
    unsigned v = (t >= off) ? sd[t - off] : 0u;
    __syncthreads();
    sd[t] += v;
    __syncthreads();
  }
  unsigned run = (t == 0) ? 0u : sd[t - 1];
  for (int j = 0; j < 32; ++j) {
    unsigned c = cnt[cbase + j];
    offs[cbase + j] = run;
    fill[cbase + j] = run;
    run += c;
  }
}

// Counting-sort scatter (order within cell arbitrary; min is order-invariant).
__global__ __launch_bounds__(256) void scatter_kernel(const float4* __restrict__ A,
                                                      const float4* __restrict__ G,
                                                      const unsigned* __restrict__ cellA,
                                                      const unsigned* __restrict__ cellG,
                                                      unsigned* __restrict__ fill,
                                                      float4* __restrict__ sA,
                                                      unsigned* __restrict__ iA,
                                                      float4* __restrict__ sG,
                                                      unsigned* __restrict__ iG) {
  int i = blockIdx.x * 256 + threadIdx.x;
  int b = i >> 13;
  unsigned n = (unsigned)(i & (N - 1));
  unsigned ca = cellA[i];
  unsigned slot = atomicAdd(&fill[((unsigned)(0*4 + b) << 15) + ca], 1u);
  sA[(b << 13) + slot] = A[i]; iA[(b << 13) + slot] = n;
  unsigned cg = cellG[i];
  slot = atomicAdd(&fill[((unsigned)(1*4 + b) << 15) + cg], 1u);
  sG[(b << 13) + slot] = G[i]; iG[(b << 13) + slot] = n;
}

// Grid NN query, BOUNDED: scan exactly the 27-cell (R=1) box. 4 lanes/query.
// Resolved iff best-d <= CS^2 (points outside a Chebyshev-2 cell ring are
// >= CS away, valid under clamping at both ends). Unresolved -> compact list
// for the brute-force fallback. Single-writer plain stores to m2/m1.
__global__ __launch_bounds__(256) void query_kernel(const float4* __restrict__ sA,
                                                    const unsigned* __restrict__ iA,
                                                    const float4* __restrict__ sG,
                                                    const unsigned* __restrict__ iG,
                                                    const unsigned* __restrict__ offs,
                                                    const unsigned* __restrict__ cnt,
                                                    unsigned long long* __restrict__ m2,
                                                    unsigned* __restrict__ m1,
                                                    unsigned* __restrict__ flist,
                                                    float* __restrict__ sums) {
  const int t = blockIdx.x * 256 + threadIdx.x;    // 262144 threads
  const int sub = t & 3;
  const int p = t >> 2;
  const int which = p >> 15;
  const int q = p & 32767;
  const int b = q >> 13, j = q & 8191;
  const float4* __restrict__ sq   = which ? sA : sG;
  const unsigned* __restrict__ sqi = which ? iA : iG;
  const float4* __restrict__ db   = which ? sG : sA;
  const unsigned* __restrict__ dbi = which ? iG : iA;
  const unsigned gb = ((unsigned)((which << 2) + b)) << 15;   // db grid base
  float4 qr = sq[(b << 13) + j];
  unsigned orig = sqi[(b << 13) + j];
  const float px = -0.5f * qr.x, py = -0.5f * qr.y, pz = -0.5f * qr.z, w = qr.w;
  const int cx = clamp31((int)floorf((px - LO) * INV));
  const int cy = clamp31((int)floorf((py - LO) * INV));
  const int cz = clamp31((int)floorf((pz - LO) * INV));
  const float4* __restrict__ dbb = db + (b << 13);
  const unsigned* __restrict__ dbib = dbi + (b << 13);
  unsigned long long best = ~0ULL;
  const int x0 = cx - 1 < 0 ? 0 : cx - 1, x1 = cx + 1 > 31 ? 31 : cx + 1;
  const int y0 = cy - 1 < 0 ? 0 : cy - 1, y1 = cy + 1 > 31 ? 31 : cy + 1;
  const int z0 = cz - 1 < 0 ? 0 : cz - 1, z1 = cz + 1 > 31 ? 31 : cz + 1;
  for (int zz = z0; zz <= z1; ++zz) {
    for (int yy = y0; yy <= y1; ++yy) {
      const unsigned rowb = gb + (unsigned)((zz << 10) | (yy << 5));
      const int s = (int)offs[rowb + x0];
      const int e = (int)(offs[rowb + x1] + cnt[rowb + x1]);
      for (int k = s + sub; k < e; k += 4) {
        float4 c = dbb[k];
        float d = w + fmaf(px, c.x, fmaf(py, c.y, fmaf(pz, c.z, c.w)));
        unsigned long long key = ((unsigned long long)fkey(d) << 32) | dbib[k];
        best = key < best ? key : best;
      }
    }
  }
  unsigned long long o = __shfl_xor(best, 1, 64); best = o < best ? o : best;
  o = __shfl_xor(best, 2, 64); best = o < best ? o : best;
  float bd = funkey((unsigned)(best >> 32));
  if (sub == 0) {
    if (bd <= CS * CS) {            // resolved: true NN guaranteed inside box
      if (which == 0) m2[(b << 13) + orig] = best;
      else            m1[(b << 13) + orig] = (unsigned)(best >> 32);
    } else {                        // rare (outliers): defer to brute fallback
      unsigned slot = atomicAdd((unsigned*)(sums + 28), 1u);
      flist[slot] = (unsigned)((which << 15) | (b << 13) | j);
    }
  }
}

// Brute-force fallback: one WAVE per unresolved query, grid-stride over list.
// Coalesced lane-strided float4 loads over all 8192 db points; shfl-min ladder.
__global__ __launch_bounds__(256) void fallback_kernel(const float4* __restrict__ sA,
                                                       const unsigned* __restrict__ iA,
                                                       const float4* __restrict__ sG,
                                                       const unsigned* __restrict__ iG,
                                                       const unsigned* __restrict__ flist,
                                                       const float* __restrict__ sums,
                                                       unsigned long long* __restrict__ m2,
                                                       unsigned* __restrict__ m1) {
  const unsigned count = *(const unsigned*)(sums + 28);
  const int lane = threadIdx.x & 63;
  const int wglob = (blockIdx.x * 256 + threadIdx.x) >> 6;   // 1024 waves
  for (unsigned li = wglob; li < count; li += 1024) {
    const unsigned en = flist[li];
    const int which = en >> 15, b = (en >> 13) & 3, j = en & 8191;
    const float4* __restrict__ sq   = which ? sA : sG;
    const unsigned* __restrict__ sqi = which ? iA : iG;
    const float4* __restrict__ db   = which ? sG : sA;
    const unsigned* __restrict__ dbi = which ? iG : iA;
    float4 qr = sq[(b << 13) + j];
    unsigned orig = sqi[(b << 13) + j];
    const float px = -0.5f * qr.x, py = -0.5f * qr.y, pz = -0.5f * qr.z, w = qr.w;
    const float4* __restrict__ dbb = db + (b << 13);
    const unsigned* __restrict__ dbib = dbi + (b << 13);
    unsigned long long best = ~0ULL;
    for (int k = lane; k < N; k += 64) {
      float4 c = dbb[k];
      float d = w + fmaf(px, c.x, fmaf(py, c.y, fmaf(pz, c.z, c.w)));
      unsigned long long key = ((unsigned long long)fkey(d) << 32) | dbib[k];
      best = key < best ? key : best;
    }
#pragma unroll
    for (int o = 1; o < 64; o <<= 1) {
      unsigned long long v = __shfl_xor(best, o, 64);
      best = v < best ? v : best;
    }
    if (lane == 0) {
      if (which == 0) m2[(b << 13) + orig] = best;
      else            m1[(b << 13) + orig] = (unsigned)(best >> 32);
    }
  }
}

// edgeA, 512 blocks (R14-proven):
//  blocks [0,384): edge gathers (argmin from m2 low bits), SoA store, 6 col-sums.
//  blocks [384,512): chamfer reduce of m1/m2 -> sums[0], sums[1].
__global__ __launch_bounds__(256) void edgeA_kernel(const float* __restrict__ preds,
                                                    const float* __restrict__ normals,
                                                    const int* __restrict__ edges,
                                                    const unsigned long long* __restrict__ m2,
                                                    const unsigned* __restrict__ m1,
                                                    float* __restrict__ ev,
                                                    float* __restrict__ sums) {
  __shared__ float ws[4][6];
  const int tid = threadIdx.x;
  const int wid = tid >> 6, lane = tid & 63;
  if (blockIdx.x < 384) {
    const int b = blockIdx.x / 96;
    const int e = (blockIdx.x % 96) * 256 + tid;
    int e0 = edges[2*e], e1 = edges[2*e+1];
    const float* pb = preds   + 3*(size_t)b*N;
    const float* nb = normals + 3*(size_t)b*N;
    float vx = pb[3*e0]   - pb[3*e1];
    float vy = pb[3*e0+1] - pb[3*e1+1];
    float vz = pb[3*e0+2] - pb[3*e1+2];
    unsigned ni = (unsigned)m2[b*N + e0];          // exact argmin from query
    float nx = nb[3*ni], ny = nb[3*ni+1], nz = nb[3*ni+2];
    const int be = b * E + e;
    ev[0*BE + be] = vx; ev[1*BE + be] = vy; ev[2*BE + be] = vz;
    ev[3*BE + be] = nx; ev[4*BE + be] = ny; ev[5*BE + be] = nz;
    float v[6] = {nx*nx, ny*ny, nz*nz, vx*vx, vy*vy, vz*vz};
#pragma unroll
    for (int k = 0; k < 6; ++k)
#pragma unroll
      for (int o = 32; o; o >>= 1) v[k] += __shfl_down(v[k], o, 64);
    if (lane == 0) {
#pragma unroll
      for (int k = 0; k < 6; ++k) ws[wid][k] = v[k];
    }
    __syncthreads();
    if (tid < 6) {
      const int k = tid;
      float s = ws[0][k] + ws[1][k] + ws[2][k] + ws[3][k];
      atomicAdd(&sums[(k < 3 ? 3 + k : 12 + k) + b*3], s);  // nsq: 3+b*3+d, vsq: 15+b*3+d
    }
  } else {
    int i = (blockIdx.x - 384) * 256 + tid;
    float d2 = funkey((unsigned)(m2[i] >> 32));
    float d1 = funkey(m1[i]);
#pragma unroll
    for (int o = 32; o; o >>= 1) { d2 += __shfl_down(d2, o, 64); d1 += __shfl_down(d1, o, 64); }
    if (lane == 0) { ws[wid][0] = d2; ws[wid][1] = d1; }
    __syncthreads();
    if (tid == 0) {
      atomicAdd(&sums[1], ws[0][0] + ws[1][0] + ws[2][0] + ws[3][0]);
      atomicAdd(&sums[0], ws[0][1] + ws[1][1] + ws[2][1] + ws[3][1]);
    }
  }
}

// edgeB, 384 blocks (R14-proven): cosine term + final via last-block ticket.
__global__ __launch_bounds__(256) void edgeB_kernel(const float* __restrict__ ev,
                                                    float* __restrict__ sums,
                                                    float* __restrict__ out) {
  __shared__ float ws[4];
  __shared__ bool amLast;
  const int tid = threadIdx.x;
  const int b = blockIdx.x / 96;
  const int e = (blockIdx.x % 96) * 256 + tid;
  const int be = b * E + e;
  float vx = ev[0*BE + be], vy = ev[1*BE + be], vz = ev[2*BE + be];
  float nx = ev[3*BE + be], ny = ev[4*BE + be], nz = ev[5*BE + be];
  float inn0 = 1.f / fmaxf(sqrtf(sums[3  + b*3 + 0]), 1e-12f);
  float inn1 = 1.f / fmaxf(sqrtf(sums[3  + b*3 + 1]), 1e-12f);
  float inn2 = 1.f / fmaxf(sqrtf(sums[3  + b*3 + 2]), 1e-12f);
  float inv0 = 1.f / fmaxf(sqrtf(sums[15 + b*3 + 0]), 1e-12f);
  float inv1 = 1.f / fmaxf(sqrtf(sums[15 + b*3 + 1]), 1e-12f);
  float inv2 = 1.f / fmaxf(sqrtf(sums[15 + b*3 + 2]), 1e-12f);
  float c = fabsf(nx*inn0*vx*inv0 + ny*inn1*vy*inv1 + nz*inn2*vz*inv2);
#pragma unroll
  for (int o = 32; o; o >>= 1) c += __shfl_down(c, o, 64);
  if ((tid & 63) == 0) ws[tid >> 6] = c;
  __syncthreads();
  if (tid == 0) {
    atomicAdd(&sums[2], ws[0] + ws[1] + ws[2] + ws[3]);
    __threadfence();
    unsigned old = atomicAdd((unsigned*)(sums + 30), 1u);
    amLast = (old == 383u);
  }
  __syncthreads();
  if (amLast && tid == 0) {
    float esum = 0.f;
#pragma unroll
    for (int i = 0; i < 12; ++i) esum += atomicAdd(&sums[15 + i], 0.f);
    float s0 = atomicAdd(&sums[0], 0.f), s1 = atomicAdd(&sums[1], 0.f);
    float s2 = atomicAdd(&sums[2], 0.f);
    float chamfer   = (s0 + s1) * (1.f / (float)BN);
    float edge_loss = esum * (1.f / (float)(B * E));
    float ncl       = s2 * (1.f / (float)(B * E));
    out[0] = 30000.f * chamfer + 240.f * edge_loss + 200000.f * ncl;
  }
}

} // namespace

extern "C" void kernel_launch(void* const* d_in, const int* in_sizes, int n_in,
                              void* d_out, int out_size, void* d_ws, size_t ws_size,
                              hipStream_t stream) {
  (void)in_sizes; (void)n_in; (void)out_size; (void)ws_size;
  const float* preds   = (const float*)d_in[0];
  const float* gts     = (const float*)d_in[1];
  const float* normals = (const float*)d_in[2];
  const int*   edges   = (const int*)d_in[3];
  char* ws = (char*)d_ws;
  // ws layout: A 512K | G 512K | cellA 128K | cellG 128K | cnt 1M | offs 1M |
  //            fill 1M | sA 512K | sG 512K | iA 128K | iG 128K | m2 256K |
  //            m1 128K | sums 4K | flist 256K.
  //            ev (2.25M) OVERLAYS cnt/offs/fill (dead after fallback).
  float4*             A     = (float4*)(ws);
  float4*             G     = (float4*)(ws + 0x080000);
  unsigned*           cellA = (unsigned*)(ws + 0x100000);
  unsigned*           cellG = (unsigned*)(ws + 0x120000);
  unsigned*           cnt   = (unsigned*)(ws + 0x140000);
  unsigned*           offs  = (unsigned*)(ws + 0x240000);
  unsigned*           fill  = (unsigned*)(ws + 0x340000);
  float4*             sA    = (float4*)(ws + 0x440000);
  float4*             sG    = (float4*)(ws + 0x4C0000);
  unsigned*           iA    = (unsigned*)(ws + 0x540000);
  unsigned*           iG    = (unsigned*)(ws + 0x560000);
  unsigned long long* m2    = (unsigned long long*)(ws + 0x580000);
  unsigned*           m1    = (unsigned*)(ws + 0x5C0000);
  float*              sums  = (float*)(ws + 0x5E0000);
  unsigned*           flist = (unsigned*)(ws + 0x5E1000);
  float*              ev    = (float*)(ws + 0x140000);   // overlay
  float* out = (float*)d_out;

  z0_kernel<<<dim3(256), 256, 0, stream>>>((uint4*)cnt, sums);
  prep2_kernel<<<dim3(BN/256), 256, 0, stream>>>(preds, gts, A, G, cellA, cellG, cnt);
  scan_kernel<<<dim3(8), 1024, 0, stream>>>(cnt, offs, fill);
  scatter_kernel<<<dim3(BN/256), 256, 0, stream>>>(A, G, cellA, cellG, fill, sA, iA, sG, iG);
  query_kernel<<<dim3(1024), 256, 0, stream>>>(sA, iA, sG, iG, offs, cnt, m2, m1, flist, sums);
  fallback_kernel<<<dim3(256), 256, 0, stream>>>(sA, iA, sG, iG, flist, sums, m2, m1);
  edgeA_kernel<<<dim3(512), 256, 0, stream>>>(preds, normals, edges, m2, m1, ev, sums);
  edgeB_kernel<<<dim3(384), 256, 0, stream>>>(ev, sums, out);
}

// Round 17
// 115.303 us; speedup vs baseline: 2.3130x; 1.5147x over previous
//
#include <hip/hip_runtime.h>

namespace {

constexpr int B = 4;
constexpr int N = 8192;          // power of two (N = 1<<13)
constexpr int E = 24576;
constexpr int BN = B * N;
constexpr int BE = B * E;
constexpr float LO = -4.2f;
constexpr float CS = 0.2625f;    // cell size (covers [-4.2, 4.2], 32 cells/axis)
constexpr float INV = 1.0f / 0.2625f;

// Monotonic float <-> uint mapping (total order matches float compare)
__device__ __forceinline__ unsigned fkey(float f) {
  unsigned b = __float_as_uint(f);
  return b ^ ((b & 0x80000000u) ? 0xFFFFFFFFu : 0x80000000u);
}
__device__ __forceinline__ float funkey(unsigned k) {
  unsigned b = k ^ ((k & 0x80000000u) ? 0x80000000u : 0xFFFFFFFFu);
  return __uint_as_float(b);
}
__device__ __forceinline__ int clamp31(int v) { return v < 0 ? 0 : (v > 31 ? 31 : v); }

// sums layout (floats): [0]=s1, [1]=s2, [2]=cos sum, [3..14]=nsq[b][d],
// [15..26]=vsq[b][d], [28]=stage2 count, [29]=brute count, [30]=edgeB ticket

__global__ __launch_bounds__(256) void z0_kernel(uint4* __restrict__ cnt4,
                                                 float* __restrict__ sums) {
  int i = blockIdx.x * 256 + threadIdx.x;   // 65536 threads x uint4 = 1MB
  cnt4[i] = uint4{0u, 0u, 0u, 0u};
  if (i < 32) sums[i] = 0.f;                // zeroes [28],[29],[30] too
}

// A[i] = (-2*p, |p|^2), G[i] = (-2*g, |g|^2); cell ids + histograms.
__global__ __launch_bounds__(256) void prep2_kernel(const float* __restrict__ preds,
                                                    const float* __restrict__ gts,
                                                    float4* __restrict__ A,
                                                    float4* __restrict__ G,
                                                    unsigned* __restrict__ cellA,
                                                    unsigned* __restrict__ cellG,
                                                    unsigned* __restrict__ cnt) {
  int i = blockIdx.x * 256 + threadIdx.x;
  int b = i >> 13;
  float px = preds[3*i], py = preds[3*i+1], pz = preds[3*i+2];
  float gx = gts[3*i],   gy = gts[3*i+1],  gz = gts[3*i+2];
  A[i] = make_float4(-2.f*px, -2.f*py, -2.f*pz, px*px + py*py + pz*pz);
  G[i] = make_float4(-2.f*gx, -2.f*gy, -2.f*gz, gx*gx + gy*gy + gz*gz);
  int ax = clamp31((int)floorf((px - LO) * INV));
  int ay = clamp31((int)floorf((py - LO) * INV));
  int az = clamp31((int)floorf((pz - LO) * INV));
  unsigned ca = (unsigned)((az << 10) | (ay << 5) | ax);
  int bx_ = clamp31((int)floorf((gx - LO) * INV));
  int by_ = clamp31((int)floorf((gy - LO) * INV));
  int bz_ = clamp31((int)floorf((gz - LO) * INV));
  unsigned cg = (unsigned)((bz_ << 10) | (by_ << 5) | bx_);
  cellA[i] = ca; cellG[i] = cg;
  atomicAdd(&cnt[((unsigned)(0*4 + b) << 15) + ca], 1u);   // set0 = preds
  atomicAdd(&cnt[((unsigned)(1*4 + b) << 15) + cg], 1u);   // set1 = gts
}

// Exclusive scan per (set,b) grid: 8 blocks x 1024 threads, 32 cells/thread.
// Wave-shfl scan + 2 barriers (was Hillis-Steele with 20 barriers).
__global__ __launch_bounds__(1024) void scan_kernel(const unsigned* __restrict__ cnt,
                                                    unsigned* __restrict__ offs,
                                                    unsigned* __restrict__ fill) {
  __shared__ unsigned wsum[16], wbase[16];
  const unsigned base = (unsigned)blockIdx.x << 15;
  const int t = threadIdx.x;
  const int lane = t & 63, wid = t >> 6;
  const unsigned cbase = base + (unsigned)t * 32u;
  unsigned s = 0;
  for (int j = 0; j < 32; ++j) s += cnt[cbase + j];
  unsigned v = s;                        // wave-inclusive scan
#pragma unroll
  for (int o = 1; o < 64; o <<= 1) {
    unsigned u = __shfl_up(v, o, 64);
    if (lane >= o) v += u;
  }
  if (lane == 63) wsum[wid] = v;
  __syncthreads();
  if (t == 0) {
    unsigned run = 0;
#pragma unroll
    for (int i = 0; i < 16; ++i) { wbase[i] = run; run += wsum[i]; }
  }
  __syncthreads();
  unsigned run = (v - s) + wbase[wid];   // exclusive prefix of this thread's chunk
  for (int j = 0; j < 32; ++j) {
    unsigned c = cnt[cbase + j];
    offs[cbase + j] = run;
    fill[cbase + j] = run;
    run += c;
  }
}

// Counting-sort scatter (order within cell arbitrary; min is order-invariant).
__global__ __launch_bounds__(256) void scatter_kernel(const float4* __restrict__ A,
                                                      const float4* __restrict__ G,
                                                      const unsigned* __restrict__ cellA,
                                                      const unsigned* __restrict__ cellG,
                                                      unsigned* __restrict__ fill,
                                                      float4* __restrict__ sA,
                                                      unsigned* __restrict__ iA,
                                                      float4* __restrict__ sG,
                                                      unsigned* __restrict__ iG) {
  int i = blockIdx.x * 256 + threadIdx.x;
  int b = i >> 13;
  unsigned n = (unsigned)(i & (N - 1));
  unsigned ca = cellA[i];
  unsigned slot = atomicAdd(&fill[((unsigned)(0*4 + b) << 15) + ca], 1u);
  sA[(b << 13) + slot] = A[i]; iA[(b << 13) + slot] = n;
  unsigned cg = cellG[i];
  slot = atomicAdd(&fill[((unsigned)(1*4 + b) << 15) + cg], 1u);
  sG[(b << 13) + slot] = G[i]; iG[(b << 13) + slot] = n;
}

// Stage 1: 27-cell (R=1) box, 4 lanes/query. Resolved iff bd <= CS^2
// (points outside the box differ by > CS in some coord, clamp-safe).
__global__ __launch_bounds__(256) void query_kernel(const float4* __restrict__ sA,
                                                    const unsigned* __restrict__ iA,
                                                    const float4* __restrict__ sG,
                                                    const unsigned* __restrict__ iG,
                                                    const unsigned* __restrict__ offs,
                                                    const unsigned* __restrict__ cnt,
                                                    unsigned long long* __restrict__ m2,
                                                    unsigned* __restrict__ m1,
                                                    unsigned* __restrict__ flist,
                                                    float* __restrict__ sums) {
  const int t = blockIdx.x * 256 + threadIdx.x;    // 262144 threads
  const int sub = t & 3;
  const int p = t >> 2;
  const int which = p >> 15;
  const int q = p & 32767;
  const int b = q >> 13, j = q & 8191;
  const float4* __restrict__ sq   = which ? sA : sG;
  const unsigned* __restrict__ sqi = which ? iA : iG;
  const float4* __restrict__ db   = which ? sG : sA;
  const unsigned* __restrict__ dbi = which ? iG : iA;
  const unsigned gb = ((unsigned)((which << 2) + b)) << 15;   // db grid base
  float4 qr = sq[(b << 13) + j];
  unsigned orig = sqi[(b << 13) + j];
  const float px = -0.5f * qr.x, py = -0.5f * qr.y, pz = -0.5f * qr.z, w = qr.w;
  const int cx = clamp31((int)floorf((px - LO) * INV));
  const int cy = clamp31((int)floorf((py - LO) * INV));
  const int cz = clamp31((int)floorf((pz - LO) * INV));
  const float4* __restrict__ dbb = db + (b << 13);
  const unsigned* __restrict__ dbib = dbi + (b << 13);
  unsigned long long best = ~0ULL;
  const int x0 = cx - 1 < 0 ? 0 : cx - 1, x1 = cx + 1 > 31 ? 31 : cx + 1;
  const int y0 = cy - 1 < 0 ? 0 : cy - 1, y1 = cy + 1 > 31 ? 31 : cy + 1;
  const int z0 = cz - 1 < 0 ? 0 : cz - 1, z1 = cz + 1 > 31 ? 31 : cz + 1;
  for (int zz = z0; zz <= z1; ++zz) {
    for (int yy = y0; yy <= y1; ++yy) {
      const unsigned rowb = gb + (unsigned)((zz << 10) | (yy << 5));
      const int s = (int)offs[rowb + x0];
      const int e = (int)(offs[rowb + x1] + cnt[rowb + x1]);
      for (int k = s + sub; k < e; k += 4) {
        float4 c = dbb[k];
        float d = w + fmaf(px, c.x, fmaf(py, c.y, fmaf(pz, c.z, c.w)));
        unsigned long long key = ((unsigned long long)fkey(d) << 32) | dbib[k];
        best = key < best ? key : best;
      }
    }
  }
  unsigned long long o = __shfl_xor(best, 1, 64); best = o < best ? o : best;
  o = __shfl_xor(best, 2, 64); best = o < best ? o : best;
  float bd = funkey((unsigned)(best >> 32));
  if (sub == 0) {
    if (bd <= CS * CS) {
      if (which == 0) m2[(b << 13) + orig] = best;
      else            m1[(b << 13) + orig] = (unsigned)(best >> 32);
    } else {
      unsigned slot = atomicAdd((unsigned*)(sums + 28), 1u);
      flist[slot] = (unsigned)((which << 15) | (b << 13) | j);
    }
  }
}

// Stage 2: R=2 box (125 cells = 25 rows), ONE LANE PER ROW (32-lane group per
// query) -> all row lookups + scans in parallel. Resolved iff bd <= (2CS)^2.
// Survivors (extreme outliers, ~0.5%) -> flist2 for the brute stage.
__global__ __launch_bounds__(256) void ring2_kernel(const float4* __restrict__ sA,
                                                    const unsigned* __restrict__ iA,
                                                    const float4* __restrict__ sG,
                                                    const unsigned* __restrict__ iG,
                                                    const unsigned* __restrict__ offs,
                                                    const unsigned* __restrict__ cnt,
                                                    unsigned long long* __restrict__ m2,
                                                    unsigned* __restrict__ m1,
                                                    const unsigned* __restrict__ flist,
                                                    float* __restrict__ sums,
                                                    unsigned* __restrict__ flist2) {
  const unsigned count = *(const unsigned*)(sums + 28);
  const int grp = (blockIdx.x * 256 + threadIdx.x) >> 5;   // 2048 32-lane groups
  const int l32 = threadIdx.x & 31;
  for (unsigned li = grp; li < count; li += 2048) {
    const unsigned en = flist[li];
    const int which = en >> 15, b = (en >> 13) & 3, j = en & 8191;
    const float4* __restrict__ sq   = which ? sA : sG;
    const unsigned* __restrict__ sqi = which ? iA : iG;
    const float4* __restrict__ db   = which ? sG : sA;
    const unsigned* __restrict__ dbi = which ? iG : iA;
    const unsigned gb = ((unsigned)((which << 2) + b)) << 15;
    float4 qr = sq[(b << 13) + j];
    unsigned orig = sqi[(b << 13) + j];
    const float px = -0.5f * qr.x, py = -0.5f * qr.y, pz = -0.5f * qr.z, w = qr.w;
    const int cx = clamp31((int)floorf((px - LO) * INV));
    const int cy = clamp31((int)floorf((py - LO) * INV));
    const int cz = clamp31((int)floorf((pz - LO) * INV));
    const float4* __restrict__ dbb = db + (b << 13);
    const unsigned* __restrict__ dbib = dbi + (b << 13);
    unsigned long long best = ~0ULL;
    if (l32 < 25) {
      const int zz = cz + (l32 / 5) - 2;
      const int yy = cy + (l32 % 5) - 2;
      if (zz >= 0 && zz <= 31 && yy >= 0 && yy <= 31) {
        const int x0 = cx - 2 < 0 ? 0 : cx - 2, x1 = cx + 2 > 31 ? 31 : cx + 2;
        const unsigned rowb = gb + (unsigned)((zz << 10) | (yy << 5));
        const int s = (int)offs[rowb + x0];
        const int e = (int)(offs[rowb + x1] + cnt[rowb + x1]);
        for (int k = s; k < e; ++k) {
          float4 c = dbb[k];
          float d = w + fmaf(px, c.x, fmaf(py, c.y, fmaf(pz, c.z, c.w)));
          unsigned long long key = ((unsigned long long)fkey(d) << 32) | dbib[k];
          best = key < best ? key : best;
        }
      }
    }
#pragma unroll
    for (int o = 1; o < 32; o <<= 1) {          // stays within the 32-group
      unsigned long long v = __shfl_xor(best, o, 64);
      best = v < best ? v : best;
    }
    if (l32 == 0) {
      float bd = funkey((unsigned)(best >> 32));
      if (bd <= (2.f * CS) * (2.f * CS)) {
        if (which == 0) m2[(b << 13) + orig] = best;
        else            m1[(b << 13) + orig] = (unsigned)(best >> 32);
      } else {
        unsigned slot = atomicAdd((unsigned*)(sums + 29), 1u);
        flist2[slot] = en;
      }
    }
  }
}

// Brute fallback (extreme outliers only): one wave per query, 4 independent
// loads per iteration for latency overlap.
__global__ __launch_bounds__(256) void fallback_kernel(const float4* __restrict__ sA,
                                                       const unsigned* __restrict__ iA,
                                                       const float4* __restrict__ sG,
                                                       const unsigned* __restrict__ iG,
                                                       const unsigned* __restrict__ flist2,
                                                       const float* __restrict__ sums,
                                                       unsigned long long* __restrict__ m2,
                                                       unsigned* __restrict__ m1) {
  const unsigned count = *(const unsigned*)(sums + 29);
  const int lane = threadIdx.x & 63;
  const int wglob = (blockIdx.x * 256 + threadIdx.x) >> 6;   // 1024 waves
  for (unsigned li = wglob; li < count; li += 1024) {
    const unsigned en = flist2[li];
    const int which = en >> 15, b = (en >> 13) & 3, j = en & 8191;
    const float4* __restrict__ sq   = which ? sA : sG;
    const unsigned* __restrict__ sqi = which ? iA : iG;
    const float4* __restrict__ db   = which ? sG : sA;
    const unsigned* __restrict__ dbi = which ? iG : iA;
    float4 qr = sq[(b << 13) + j];
    unsigned orig = sqi[(b << 13) + j];
    const float px = -0.5f * qr.x, py = -0.5f * qr.y, pz = -0.5f * qr.z, w = qr.w;
    const float4* __restrict__ dbb = db + (b << 13);
    const unsigned* __restrict__ dbib = dbi + (b << 13);
    unsigned long long best = ~0ULL;
    for (int k0 = 0; k0 < N; k0 += 256) {        // 32 iters x 4 independent loads
      float4 c0 = dbb[k0 + lane],       c1 = dbb[k0 + 64 + lane];
      float4 c2 = dbb[k0 + 128 + lane], c3 = dbb[k0 + 192 + lane];
      unsigned i0 = dbib[k0 + lane],       i1 = dbib[k0 + 64 + lane];
      unsigned i2 = dbib[k0 + 128 + lane], i3 = dbib[k0 + 192 + lane];
      float d0 = w + fmaf(px, c0.x, fmaf(py, c0.y, fmaf(pz, c0.z, c0.w)));
      float d1 = w + fmaf(px, c1.x, fmaf(py, c1.y, fmaf(pz, c1.z, c1.w)));
      float d2 = w + fmaf(px, c2.x, fmaf(py, c2.y, fmaf(pz, c2.z, c2.w)));
      float d3 = w + fmaf(px, c3.x, fmaf(py, c3.y, fmaf(pz, c3.z, c3.w)));
      unsigned long long k0_ = ((unsigned long long)fkey(d0) << 32) | i0;
      unsigned long long k1_ = ((unsigned long long)fkey(d1) << 32) | i1;
      unsigned long long k2_ = ((unsigned long long)fkey(d2) << 32) | i2;
      unsigned long long k3_ = ((unsigned long long)fkey(d3) << 32) | i3;
      unsigned long long m01 = k0_ < k1_ ? k0_ : k1_;
      unsigned long long m23 = k2_ < k3_ ? k2_ : k3_;
      unsigned long long m = m01 < m23 ? m01 : m23;
      best = m < best ? m : best;
    }
#pragma unroll
    for (int o = 1; o < 64; o <<= 1) {
      unsigned long long v = __shfl_xor(best, o, 64);
      best = v < best ? v : best;
    }
    if (lane == 0) {
      if (which == 0) m2[(b << 13) + orig] = best;
      else            m1[(b << 13) + orig] = (unsigned)(best >> 32);
    }
  }
}

// edgeA, 512 blocks (R14-proven):
//  blocks [0,384): edge gathers (argmin from m2 low bits), SoA store, 6 col-sums.
//  blocks [384,512): chamfer reduce of m1/m2 -> sums[0], sums[1].
__global__ __launch_bounds__(256) void edgeA_kernel(const float* __restrict__ preds,
                                                    const float* __restrict__ normals,
                                                    const int* __restrict__ edges,
                                                    const unsigned long long* __restrict__ m2,
                                                    const unsigned* __restrict__ m1,
                                                    float* __restrict__ ev,
                                                    float* __restrict__ sums) {
  __shared__ float ws[4][6];
  const int tid = threadIdx.x;
  const int wid = tid >> 6, lane = tid & 63;
  if (blockIdx.x < 384) {
    const int b = blockIdx.x / 96;
    const int e = (blockIdx.x % 96) * 256 + tid;
    int e0 = edges[2*e], e1 = edges[2*e+1];
    const float* pb = preds   + 3*(size_t)b*N;
    const float* nb = normals + 3*(size_t)b*N;
    float vx = pb[3*e0]   - pb[3*e1];
    float vy = pb[3*e0+1] - pb[3*e1+1];
    float vz = pb[3*e0+2] - pb[3*e1+2];
    unsigned ni = (unsigned)m2[b*N + e0];          // exact argmin
    float nx = nb[3*ni], ny = nb[3*ni+1], nz = nb[3*ni+2];
    const int be = b * E + e;
    ev[0*BE + be] = vx; ev[1*BE + be] = vy; ev[2*BE + be] = vz;
    ev[3*BE + be] = nx; ev[4*BE + be] = ny; ev[5*BE + be] = nz;
    float v[6] = {nx*nx, ny*ny, nz*nz, vx*vx, vy*vy, vz*vz};
#pragma unroll
    for (int k = 0; k < 6; ++k)
#pragma unroll
      for (int o = 32; o; o >>= 1) v[k] += __shfl_down(v[k], o, 64);
    if (lane == 0) {
#pragma unroll
      for (int k = 0; k < 6; ++k) ws[wid][k] = v[k];
    }
    __syncthreads();
    if (tid < 6) {
      const int k = tid;
      float s = ws[0][k] + ws[1][k] + ws[2][k] + ws[3][k];
      atomicAdd(&sums[(k < 3 ? 3 + k : 12 + k) + b*3], s);  // nsq: 3+b*3+d, vsq: 15+b*3+d
    }
  } else {
    int i = (blockIdx.x - 384) * 256 + tid;
    float d2 = funkey((unsigned)(m2[i] >> 32));
    float d1 = funkey(m1[i]);
#pragma unroll
    for (int o = 32; o; o >>= 1) { d2 += __shfl_down(d2, o, 64); d1 += __shfl_down(d1, o, 64); }
    if (lane == 0) { ws[wid][0] = d2; ws[wid][1] = d1; }
    __syncthreads();
    if (tid == 0) {
      atomicAdd(&sums[1], ws[0][0] + ws[1][0] + ws[2][0] + ws[3][0]);
      atomicAdd(&sums[0], ws[0][1] + ws[1][1] + ws[2][1] + ws[3][1]);
    }
  }
}

// edgeB, 384 blocks (R14-proven): cosine term + final via last-block ticket.
__global__ __launch_bounds__(256) void edgeB_kernel(const float* __restrict__ ev,
                                                    float* __restrict__ sums,
                                                    float* __restrict__ out) {
  __shared__ float ws[4];
  __shared__ bool amLast;
  const int tid = threadIdx.x;
  const int b = blockIdx.x / 96;
  const int e = (blockIdx.x % 96) * 256 + tid;
  const int be = b * E + e;
  float vx = ev[0*BE + be], vy = ev[1*BE + be], vz = ev[2*BE + be];
  float nx = ev[3*BE + be], ny = ev[4*BE + be], nz = ev[5*BE + be];
  float inn0 = 1.f / fmaxf(sqrtf(sums[3  + b*3 + 0]), 1e-12f);
  float inn1 = 1.f / fmaxf(sqrtf(sums[3  + b*3 + 1]), 1e-12f);
  float inn2 = 1.f / fmaxf(sqrtf(sums[3  + b*3 + 2]), 1e-12f);
  float inv0 = 1.f / fmaxf(sqrtf(sums[15 + b*3 + 0]), 1e-12f);
  float inv1 = 1.f / fmaxf(sqrtf(sums[15 + b*3 + 1]), 1e-12f);
  float inv2 = 1.f / fmaxf(sqrtf(sums[15 + b*3 + 2]), 1e-12f);
  float c = fabsf(nx*inn0*vx*inv0 + ny*inn1*vy*inv1 + nz*inn2*vz*inv2);
#pragma unroll
  for (int o = 32; o; o >>= 1) c += __shfl_down(c, o, 64);
  if ((tid & 63) == 0) ws[tid >> 6] = c;
  __syncthreads();
  if (tid == 0) {
    atomicAdd(&sums[2], ws[0] + ws[1] + ws[2] + ws[3]);
    __threadfence();
    unsigned old = atomicAdd((unsigned*)(sums + 30), 1u);
    amLast = (old == 383u);
  }
  __syncthreads();
  if (amLast && tid == 0) {
    float esum = 0.f;
#pragma unroll
    for (int i = 0; i < 12; ++i) esum += atomicAdd(&sums[15 + i], 0.f);
    float s0 = atomicAdd(&sums[0], 0.f), s1 = atomicAdd(&sums[1], 0.f);
    float s2 = atomicAdd(&sums[2], 0.f);
    float chamfer   = (s0 + s1) * (1.f / (float)BN);
    float edge_loss = esum * (1.f / (float)(B * E));
    float ncl       = s2 * (1.f / (float)(B * E));
    out[0] = 30000.f * chamfer + 240.f * edge_loss + 200000.f * ncl;
  }
}

} // namespace

extern "C" void kernel_launch(void* const* d_in, const int* in_sizes, int n_in,
                              void* d_out, int out_size, void* d_ws, size_t ws_size,
                              hipStream_t stream) {
  (void)in_sizes; (void)n_in; (void)out_size; (void)ws_size;
  const float* preds   = (const float*)d_in[0];
  const float* gts     = (const float*)d_in[1];
  const float* normals = (const float*)d_in[2];
  const int*   edges   = (const int*)d_in[3];
  char* ws = (char*)d_ws;
  // ws layout: A 512K | G 512K | cellA 128K | cellG 128K | cnt 1M | offs 1M |
  //            fill 1M | sA 512K | sG 512K | iA 128K | iG 128K | m2 256K |
  //            m1 128K | sums 4K | flist 256K | flist2 256K.
  //            ev (2.25M) OVERLAYS cnt/offs/fill (dead after fallback).
  float4*             A     = (float4*)(ws);
  float4*             G     = (float4*)(ws + 0x080000);
  unsigned*           cellA = (unsigned*)(ws + 0x100000);
  unsigned*           cellG = (unsigned*)(ws + 0x120000);
  unsigned*           cnt   = (unsigned*)(ws + 0x140000);
  unsigned*           offs  = (unsigned*)(ws + 0x240000);
  unsigned*           fill  = (unsigned*)(ws + 0x340000);
  float4*             sA    = (float4*)(ws + 0x440000);
  float4*             sG    = (float4*)(ws + 0x4C0000);
  unsigned*           iA    = (unsigned*)(ws + 0x540000);
  unsigned*           iG    = (unsigned*)(ws + 0x560000);
  unsigned long long* m2    = (unsigned long long*)(ws + 0x580000);
  unsigned*           m1    = (unsigned*)(ws + 0x5C0000);
  float*              sums  = (float*)(ws + 0x5E0000);
  unsigned*           flist = (unsigned*)(ws + 0x5E1000);
  unsigned*           flist2= (unsigned*)(ws + 0x621000);
  float*              ev    = (float*)(ws + 0x140000);   // overlay
  float* out = (float*)d_out;

  z0_kernel<<<dim3(256), 256, 0, stream>>>((uint4*)cnt, sums);
  prep2_kernel<<<dim3(BN/256), 256, 0, stream>>>(preds, gts, A, G, cellA, cellG, cnt);
  scan_kernel<<<dim3(8), 1024, 0, stream>>>(cnt, offs, fill);
  scatter_kernel<<<dim3(BN/256), 256, 0, stream>>>(A, G, cellA, cellG, fill, sA, iA, sG, iG);
  query_kernel<<<dim3(1024), 256, 0, stream>>>(sA, iA, sG, iG, offs, cnt, m2, m1, flist, sums);
  ring2_kernel<<<dim3(256), 256, 0, stream>>>(sA, iA, sG, iG, offs, cnt, m2, m1, flist, sums, flist2);
  fallback_kernel<<<dim3(256), 256, 0, stream>>>(sA, iA, sG, iG, flist2, sums, m2, m1);
  edgeA_kernel<<<dim3(512), 256, 0, stream>>>(preds, normals, edges, m2, m1, ev, sums);
  edgeB_kernel<<<dim3(384), 256, 0, stream>>>(ev, sums, out);
}

// Round 18
// 114.787 us; speedup vs baseline: 2.3233x; 1.0045x over previous
//
#include <hip/hip_runtime.h>

namespace {

constexpr int B = 4;
constexpr int N = 8192;          // power of two (N = 1<<13)
constexpr int E = 24576;
constexpr int BN = B * N;
constexpr int BE = B * E;
constexpr float LO = -4.2f;
constexpr float CS = 0.2625f;    // cell size (covers [-4.2, 4.2], 32 cells/axis)
constexpr float INV = 1.0f / 0.2625f;

// Monotonic float <-> uint mapping (total order matches float compare)
__device__ __forceinline__ unsigned fkey(float f) {
  unsigned b = __float_as_uint(f);
  return b ^ ((b & 0x80000000u) ? 0xFFFFFFFFu : 0x80000000u);
}
__device__ __forceinline__ float funkey(unsigned k) {
  unsigned b = k ^ ((k & 0x80000000u) ? 0x80000000u : 0xFFFFFFFFu);
  return __uint_as_float(b);
}
__device__ __forceinline__ int clamp31(int v) { return v < 0 ? 0 : (v > 31 ? 31 : v); }

// sums layout (floats): [0]=s1, [1]=s2, [2]=cos sum, [3..14]=nsq[b][d],
// [15..26]=vsq[b][d], [28]=stage2 count, [29]=brute count, [30]=edgeB ticket

// A[i] = (-2*p, |p|^2), G[i] = (-2*g, |g|^2); cell ids + histograms; zero sums.
__global__ __launch_bounds__(256) void prep2_kernel(const float* __restrict__ preds,
                                                    const float* __restrict__ gts,
                                                    float4* __restrict__ A,
                                                    float4* __restrict__ G,
                                                    unsigned* __restrict__ cellA,
                                                    unsigned* __restrict__ cellG,
                                                    unsigned* __restrict__ cnt,
                                                    float* __restrict__ sums) {
  int i = blockIdx.x * 256 + threadIdx.x;
  int b = i >> 13;
  float px = preds[3*i], py = preds[3*i+1], pz = preds[3*i+2];
  float gx = gts[3*i],   gy = gts[3*i+1],  gz = gts[3*i+2];
  A[i] = make_float4(-2.f*px, -2.f*py, -2.f*pz, px*px + py*py + pz*pz);
  G[i] = make_float4(-2.f*gx, -2.f*gy, -2.f*gz, gx*gx + gy*gy + gz*gz);
  int ax = clamp31((int)floorf((px - LO) * INV));
  int ay = clamp31((int)floorf((py - LO) * INV));
  int az = clamp31((int)floorf((pz - LO) * INV));
  unsigned ca = (unsigned)((az << 10) | (ay << 5) | ax);
  int bx_ = clamp31((int)floorf((gx - LO) * INV));
  int by_ = clamp31((int)floorf((gy - LO) * INV));
  int bz_ = clamp31((int)floorf((gz - LO) * INV));
  unsigned cg = (unsigned)((bz_ << 10) | (by_ << 5) | bx_);
  cellA[i] = ca; cellG[i] = cg;
  atomicAdd(&cnt[((unsigned)(0*4 + b) << 15) + ca], 1u);   // set0 = preds
  atomicAdd(&cnt[((unsigned)(1*4 + b) << 15) + cg], 1u);   // set1 = gts
  if (i < 32) sums[i] = 0.f;                // zeroes [28],[29],[30] too
}

// Exclusive scan per (set,b) grid: 8 blocks x 1024 threads, 32 cells/thread.
// Wave-shfl scan + 2 barriers.
__global__ __launch_bounds__(1024) void scan_kernel(const unsigned* __restrict__ cnt,
                                                    unsigned* __restrict__ offs,
                                                    unsigned* __restrict__ fill) {
  __shared__ unsigned wsum[16], wbase[16];
  const unsigned base = (unsigned)blockIdx.x << 15;
  const int t = threadIdx.x;
  const int lane = t & 63, wid = t >> 6;
  const unsigned cbase = base + (unsigned)t * 32u;
  unsigned s = 0;
  for (int j = 0; j < 32; ++j) s += cnt[cbase + j];
  unsigned v = s;                        // wave-inclusive scan
#pragma unroll
  for (int o = 1; o < 64; o <<= 1) {
    unsigned u = __shfl_up(v, o, 64);
    if (lane >= o) v += u;
  }
  if (lane == 63) wsum[wid] = v;
  __syncthreads();
  if (t == 0) {
    unsigned run = 0;
#pragma unroll
    for (int i = 0; i < 16; ++i) { wbase[i] = run; run += wsum[i]; }
  }
  __syncthreads();
  unsigned run = (v - s) + wbase[wid];   // exclusive prefix of this thread's chunk
  for (int j = 0; j < 32; ++j) {
    unsigned c = cnt[cbase + j];
    offs[cbase + j] = run;
    fill[cbase + j] = run;
    run += c;
  }
}

// Counting-sort scatter (order within cell arbitrary; min is order-invariant).
__global__ __launch_bounds__(256) void scatter_kernel(const float4* __restrict__ A,
                                                      const float4* __restrict__ G,
                                                      const unsigned* __restrict__ cellA,
                                                      const unsigned* __restrict__ cellG,
                                                      unsigned* __restrict__ fill,
                                                      float4* __restrict__ sA,
                                                      unsigned* __restrict__ iA,
                                                      float4* __restrict__ sG,
                                                      unsigned* __restrict__ iG) {
  int i = blockIdx.x * 256 + threadIdx.x;
  int b = i >> 13;
  unsigned n = (unsigned)(i & (N - 1));
  unsigned ca = cellA[i];
  unsigned slot = atomicAdd(&fill[((unsigned)(0*4 + b) << 15) + ca], 1u);
  sA[(b << 13) + slot] = A[i]; iA[(b << 13) + slot] = n;
  unsigned cg = cellG[i];
  slot = atomicAdd(&fill[((unsigned)(1*4 + b) << 15) + cg], 1u);
  sG[(b << 13) + slot] = G[i]; iG[(b << 13) + slot] = n;
}

// Stage 1: 27-cell (R=1) box, 8 lanes/query (524288 threads, 2048 blocks).
// Resolved iff bd <= CS^2 (points outside box differ by > CS in some coord,
// clamp-safe: clamped edge cells only extend outward past the inner boundary).
__global__ __launch_bounds__(256) void query_kernel(const float4* __restrict__ sA,
                                                    const unsigned* __restrict__ iA,
                                                    const float4* __restrict__ sG,
                                                    const unsigned* __restrict__ iG,
                                                    const unsigned* __restrict__ offs,
                                                    const unsigned* __restrict__ cnt,
                                                    unsigned long long* __restrict__ m2,
                                                    unsigned* __restrict__ m1,
                                                    unsigned* __restrict__ flist,
                                                    float* __restrict__ sums) {
  const int t = blockIdx.x * 256 + threadIdx.x;
  const int sub = t & 7;
  const int p = t >> 3;
  const int which = p >> 15;
  const int q = p & 32767;
  const int b = q >> 13, j = q & 8191;
  const float4* __restrict__ sq   = which ? sA : sG;
  const unsigned* __restrict__ sqi = which ? iA : iG;
  const float4* __restrict__ db   = which ? sG : sA;
  const unsigned* __restrict__ dbi = which ? iG : iA;
  const unsigned gb = ((unsigned)((which << 2) + b)) << 15;   // db grid base
  float4 qr = sq[(b << 13) + j];
  unsigned orig = sqi[(b << 13) + j];
  const float px = -0.5f * qr.x, py = -0.5f * qr.y, pz = -0.5f * qr.z, w = qr.w;
  const int cx = clamp31((int)floorf((px - LO) * INV));
  const int cy = clamp31((int)floorf((py - LO) * INV));
  const int cz = clamp31((int)floorf((pz - LO) * INV));
  const float4* __restrict__ dbb = db + (b << 13);
  const unsigned* __restrict__ dbib = dbi + (b << 13);
  unsigned long long best = ~0ULL;
  const int x0 = cx - 1 < 0 ? 0 : cx - 1, x1 = cx + 1 > 31 ? 31 : cx + 1;
  const int y0 = cy - 1 < 0 ? 0 : cy - 1, y1 = cy + 1 > 31 ? 31 : cy + 1;
  const int z0 = cz - 1 < 0 ? 0 : cz - 1, z1 = cz + 1 > 31 ? 31 : cz + 1;
  for (int zz = z0; zz <= z1; ++zz) {
    for (int yy = y0; yy <= y1; ++yy) {
      const unsigned rowb = gb + (unsigned)((zz << 10) | (yy << 5));
      const int s = (int)offs[rowb + x0];
      const int e = (int)(offs[rowb + x1] + cnt[rowb + x1]);
      for (int k = s + sub; k < e; k += 8) {
        float4 c = dbb[k];
        float d = w + fmaf(px, c.x, fmaf(py, c.y, fmaf(pz, c.z, c.w)));
        unsigned long long key = ((unsigned long long)fkey(d) << 32) | dbib[k];
        best = key < best ? key : best;
      }
    }
  }
  unsigned long long o = __shfl_xor(best, 1, 64); best = o < best ? o : best;
  o = __shfl_xor(best, 2, 64); best = o < best ? o : best;
  o = __shfl_xor(best, 4, 64); best = o < best ? o : best;
  float bd = funkey((unsigned)(best >> 32));
  if (sub == 0) {
    if (bd <= CS * CS) {
      if (which == 0) m2[(b << 13) + orig] = best;
      else            m1[(b << 13) + orig] = (unsigned)(best >> 32);
    } else {
      unsigned slot = atomicAdd((unsigned*)(sums + 28), 1u);
      flist[slot] = (unsigned)((which << 15) | (b << 13) | j);
    }
  }
}

// Stage 2: R=2 box (125 cells = 25 rows), ONE WAVE PER QUERY (16384 waves),
// lanes 0..24 each own one (y,z) row -> all lookups+scans in parallel.
// Resolved iff bd <= (2CS)^2; survivors -> flist2 for brute.
__global__ __launch_bounds__(256) void ring2_kernel(const float4* __restrict__ sA,
                                                    const unsigned* __restrict__ iA,
                                                    const float4* __restrict__ sG,
                                                    const unsigned* __restrict__ iG,
                                                    const unsigned* __restrict__ offs,
                                                    const unsigned* __restrict__ cnt,
                                                    unsigned long long* __restrict__ m2,
                                                    unsigned* __restrict__ m1,
                                                    const unsigned* __restrict__ flist,
                                                    float* __restrict__ sums,
                                                    unsigned* __restrict__ flist2) {
  const unsigned count = *(const unsigned*)(sums + 28);
  const int lane = threadIdx.x & 63;
  const int wv = (blockIdx.x * 256 + threadIdx.x) >> 6;   // 16384 waves
  for (unsigned li = wv; li < count; li += 16384) {
    const unsigned en = flist[li];
    const int which = en >> 15, b = (en >> 13) & 3, j = en & 8191;
    const float4* __restrict__ sq   = which ? sA : sG;
    const unsigned* __restrict__ sqi = which ? iA : iG;
    const float4* __restrict__ db   = which ? sG : sA;
    const unsigned* __restrict__ dbi = which ? iG : iA;
    const unsigned gb = ((unsigned)((which << 2) + b)) << 15;
    float4 qr = sq[(b << 13) + j];
    unsigned orig = sqi[(b << 13) + j];
    const float px = -0.5f * qr.x, py = -0.5f * qr.y, pz = -0.5f * qr.z, w = qr.w;
    const int cx = clamp31((int)floorf((px - LO) * INV));
    const int cy = clamp31((int)floorf((py - LO) * INV));
    const int cz = clamp31((int)floorf((pz - LO) * INV));
    const float4* __restrict__ dbb = db + (b << 13);
    const unsigned* __restrict__ dbib = dbi + (b << 13);
    unsigned long long best = ~0ULL;
    if (lane < 25) {
      const int zz = cz + (lane / 5) - 2;
      const int yy = cy + (lane % 5) - 2;
      if (zz >= 0 && zz <= 31 && yy >= 0 && yy <= 31) {
        const int x0 = cx - 2 < 0 ? 0 : cx - 2, x1 = cx + 2 > 31 ? 31 : cx + 2;
        const unsigned rowb = gb + (unsigned)((zz << 10) | (yy << 5));
        const int s = (int)offs[rowb + x0];
        const int e = (int)(offs[rowb + x1] + cnt[rowb + x1]);
        for (int k = s; k < e; ++k) {
          float4 c = dbb[k];
          float d = w + fmaf(px, c.x, fmaf(py, c.y, fmaf(pz, c.z, c.w)));
          unsigned long long key = ((unsigned long long)fkey(d) << 32) | dbib[k];
          best = key < best ? key : best;
        }
      }
    }
#pragma unroll
    for (int o = 1; o < 64; o <<= 1) {
      unsigned long long v = __shfl_xor(best, o, 64);
      best = v < best ? v : best;
    }
    if (lane == 0) {
      float bd = funkey((unsigned)(best >> 32));
      if (bd <= (2.f * CS) * (2.f * CS)) {
        if (which == 0) m2[(b << 13) + orig] = best;
        else            m1[(b << 13) + orig] = (unsigned)(best >> 32);
      } else {
        unsigned slot = atomicAdd((unsigned*)(sums + 29), 1u);
        flist2[slot] = en;
      }
    }
  }
}

// Brute (extreme outliers): ONE BLOCK per query, coalesced full-db scan,
// 4 independent loads/iter, two-level reduce.
__global__ __launch_bounds__(256) void brute_kernel(const float4* __restrict__ sA,
                                                    const unsigned* __restrict__ iA,
                                                    const float4* __restrict__ sG,
                                                    const unsigned* __restrict__ iG,
                                                    const unsigned* __restrict__ flist2,
                                                    const float* __restrict__ sums,
                                                    unsigned long long* __restrict__ m2,
                                                    unsigned* __restrict__ m1) {
  __shared__ unsigned long long red[4];
  const unsigned count = *(const unsigned*)(sums + 29);
  const int tid = threadIdx.x;
  const int lane = tid & 63, wid = tid >> 6;
  for (unsigned qi = blockIdx.x; qi < count; qi += gridDim.x) {
    const unsigned en = flist2[qi];
    const int which = en >> 15, b = (en >> 13) & 3, j = en & 8191;
    const float4* __restrict__ sq   = which ? sA : sG;
    const unsigned* __restrict__ sqi = which ? iA : iG;
    const float4* __restrict__ db   = which ? sG : sA;
    const unsigned* __restrict__ dbi = which ? iG : iA;
    float4 qr = sq[(b << 13) + j];
    unsigned orig = sqi[(b << 13) + j];
    const float px = -0.5f * qr.x, py = -0.5f * qr.y, pz = -0.5f * qr.z, w = qr.w;
    const float4* __restrict__ dbb = db + (b << 13);
    const unsigned* __restrict__ dbib = dbi + (b << 13);
    unsigned long long best = ~0ULL;
    for (int k0 = 0; k0 < N; k0 += 1024) {       // 8 iters x 4 independent loads
      float4 c0 = dbb[k0 + tid],       c1 = dbb[k0 + 256 + tid];
      float4 c2 = dbb[k0 + 512 + tid], c3 = dbb[k0 + 768 + tid];
      unsigned i0 = dbib[k0 + tid],       i1 = dbib[k0 + 256 + tid];
      unsigned i2 = dbib[k0 + 512 + tid], i3 = dbib[k0 + 768 + tid];
      float d0 = w + fmaf(px, c0.x, fmaf(py, c0.y, fmaf(pz, c0.z, c0.w)));
      float d1 = w + fmaf(px, c1.x, fmaf(py, c1.y, fmaf(pz, c1.z, c1.w)));
      float d2 = w + fmaf(px, c2.x, fmaf(py, c2.y, fmaf(pz, c2.z, c2.w)));
      float d3 = w + fmaf(px, c3.x, fmaf(py, c3.y, fmaf(pz, c3.z, c3.w)));
      unsigned long long k0_ = ((unsigned long long)fkey(d0) << 32) | i0;
      unsigned long long k1_ = ((unsigned long long)fkey(d1) << 32) | i1;
      unsigned long long k2_ = ((unsigned long long)fkey(d2) << 32) | i2;
      unsigned long long k3_ = ((unsigned long long)fkey(d3) << 32) | i3;
      unsigned long long m01 = k0_ < k1_ ? k0_ : k1_;
      unsigned long long m23 = k2_ < k3_ ? k2_ : k3_;
      unsigned long long m = m01 < m23 ? m01 : m23;
      best = m < best ? m : best;
    }
#pragma unroll
    for (int o = 1; o < 64; o <<= 1) {
      unsigned long long v = __shfl_xor(best, o, 64);
      best = v < best ? v : best;
    }
    if (lane == 0) red[wid] = best;
    __syncthreads();
    if (tid == 0) {
      unsigned long long m01 = red[0] < red[1] ? red[0] : red[1];
      unsigned long long m23 = red[2] < red[3] ? red[2] : red[3];
      unsigned long long m = m01 < m23 ? m01 : m23;
      if (which == 0) m2[(b << 13) + orig] = m;
      else            m1[(b << 13) + orig] = (unsigned)(m >> 32);
    }
    __syncthreads();
  }
}

// edgeA, 512 blocks (R14-proven):
//  blocks [0,384): edge gathers (argmin from m2 low bits), SoA store, 6 col-sums.
//  blocks [384,512): chamfer reduce of m1/m2 -> sums[0], sums[1].
__global__ __launch_bounds__(256) void edgeA_kernel(const float* __restrict__ preds,
                                                    const float* __restrict__ normals,
                                                    const int* __restrict__ edges,
                                                    const unsigned long long* __restrict__ m2,
                                                    const unsigned* __restrict__ m1,
                                                    float* __restrict__ ev,
                                                    float* __restrict__ sums) {
  __shared__ float ws[4][6];
  const int tid = threadIdx.x;
  const int wid = tid >> 6, lane = tid & 63;
  if (blockIdx.x < 384) {
    const int b = blockIdx.x / 96;
    const int e = (blockIdx.x % 96) * 256 + tid;
    int e0 = edges[2*e], e1 = edges[2*e+1];
    const float* pb = preds   + 3*(size_t)b*N;
    const float* nb = normals + 3*(size_t)b*N;
    float vx = pb[3*e0]   - pb[3*e1];
    float vy = pb[3*e0+1] - pb[3*e1+1];
    float vz = pb[3*e0+2] - pb[3*e1+2];
    unsigned ni = (unsigned)m2[b*N + e0];          // exact argmin
    float nx = nb[3*ni], ny = nb[3*ni+1], nz = nb[3*ni+2];
    const int be = b * E + e;
    ev[0*BE + be] = vx; ev[1*BE + be] = vy; ev[2*BE + be] = vz;
    ev[3*BE + be] = nx; ev[4*BE + be] = ny; ev[5*BE + be] = nz;
    float v[6] = {nx*nx, ny*ny, nz*nz, vx*vx, vy*vy, vz*vz};
#pragma unroll
    for (int k = 0; k < 6; ++k)
#pragma unroll
      for (int o = 32; o; o >>= 1) v[k] += __shfl_down(v[k], o, 64);
    if (lane == 0) {
#pragma unroll
      for (int k = 0; k < 6; ++k) ws[wid][k] = v[k];
    }
    __syncthreads();
    if (tid < 6) {
      const int k = tid;
      float s = ws[0][k] + ws[1][k] + ws[2][k] + ws[3][k];
      atomicAdd(&sums[(k < 3 ? 3 + k : 12 + k) + b*3], s);  // nsq: 3+b*3+d, vsq: 15+b*3+d
    }
  } else {
    int i = (blockIdx.x - 384) * 256 + tid;
    float d2 = funkey((unsigned)(m2[i] >> 32));
    float d1 = funkey(m1[i]);
#pragma unroll
    for (int o = 32; o; o >>= 1) { d2 += __shfl_down(d2, o, 64); d1 += __shfl_down(d1, o, 64); }
    if (lane == 0) { ws[wid][0] = d2; ws[wid][1] = d1; }
    __syncthreads();
    if (tid == 0) {
      atomicAdd(&sums[1], ws[0][0] + ws[1][0] + ws[2][0] + ws[3][0]);
      atomicAdd(&sums[0], ws[0][1] + ws[1][1] + ws[2][1] + ws[3][1]);
    }
  }
}

// edgeB, 384 blocks (R14-proven): cosine term + final via last-block ticket.
__global__ __launch_bounds__(256) void edgeB_kernel(const float* __restrict__ ev,
                                                    float* __restrict__ sums,
                                                    float* __restrict__ out) {
  __shared__ float ws[4];
  __shared__ bool amLast;
  const int tid = threadIdx.x;
  const int b = blockIdx.x / 96;
  const int e = (blockIdx.x % 96) * 256 + tid;
  const int be = b * E + e;
  float vx = ev[0*BE + be], vy = ev[1*BE + be], vz = ev[2*BE + be];
  float nx = ev[3*BE + be], ny = ev[4*BE + be], nz = ev[5*BE + be];
  float inn0 = 1.f / fmaxf(sqrtf(sums[3  + b*3 + 0]), 1e-12f);
  float inn1 = 1.f / fmaxf(sqrtf(sums[3  + b*3 + 1]), 1e-12f);
  float inn2 = 1.f / fmaxf(sqrtf(sums[3  + b*3 + 2]), 1e-12f);
  float inv0 = 1.f / fmaxf(sqrtf(sums[15 + b*3 + 0]), 1e-12f);
  float inv1 = 1.f / fmaxf(sqrtf(sums[15 + b*3 + 1]), 1e-12f);
  float inv2 = 1.f / fmaxf(sqrtf(sums[15 + b*3 + 2]), 1e-12f);
  float c = fabsf(nx*inn0*vx*inv0 + ny*inn1*vy*inv1 + nz*inn2*vz*inv2);
#pragma unroll
  for (int o = 32; o; o >>= 1) c += __shfl_down(c, o, 64);
  if ((tid & 63) == 0) ws[tid >> 6] = c;
  __syncthreads();
  if (tid == 0) {
    atomicAdd(&sums[2], ws[0] + ws[1] + ws[2] + ws[3]);
    __threadfence();
    unsigned old = atomicAdd((unsigned*)(sums + 30), 1u);
    amLast = (old == 383u);
  }
  __syncthreads();
  if (amLast && tid == 0) {
    float esum = 0.f;
#pragma unroll
    for (int i = 0; i < 12; ++i) esum += atomicAdd(&sums[15 + i], 0.f);
    float s0 = atomicAdd(&sums[0], 0.f), s1 = atomicAdd(&sums[1], 0.f);
    float s2 = atomicAdd(&sums[2], 0.f);
    float chamfer   = (s0 + s1) * (1.f / (float)BN);
    float edge_loss = esum * (1.f / (float)(B * E));
    float ncl       = s2 * (1.f / (float)(B * E));
    out[0] = 30000.f * chamfer + 240.f * edge_loss + 200000.f * ncl;
  }
}

} // namespace

extern "C" void kernel_launch(void* const* d_in, const int* in_sizes, int n_in,
                              void* d_out, int out_size, void* d_ws, size_t ws_size,
                              hipStream_t stream) {
  (void)in_sizes; (void)n_in; (void)out_size; (void)ws_size;
  const float* preds   = (const float*)d_in[0];
  const float* gts     = (const float*)d_in[1];
  const float* normals = (const float*)d_in[2];
  const int*   edges   = (const int*)d_in[3];
  char* ws = (char*)d_ws;
  // ws layout: A 512K | G 512K | cellA 128K | cellG 128K | cnt 1M | offs 1M |
  //            fill 1M | sA 512K | sG 512K | iA 128K | iG 128K | m2 256K |
  //            m1 128K | sums 4K | flist 256K | flist2 256K.
  //            ev (2.25M) OVERLAYS cnt/offs/fill (dead after brute).
  float4*             A     = (float4*)(ws);
  float4*             G     = (float4*)(ws + 0x080000);
  unsigned*           cellA = (unsigned*)(ws + 0x100000);
  unsigned*           cellG = (unsigned*)(ws + 0x120000);
  unsigned*           cnt   = (unsigned*)(ws + 0x140000);
  unsigned*           offs  = (unsigned*)(ws + 0x240000);
  unsigned*           fill  = (unsigned*)(ws + 0x340000);
  float4*             sA    = (float4*)(ws + 0x440000);
  float4*             sG    = (float4*)(ws + 0x4C0000);
  unsigned*           iA    = (unsigned*)(ws + 0x540000);
  unsigned*           iG    = (unsigned*)(ws + 0x560000);
  unsigned long long* m2    = (unsigned long long*)(ws + 0x580000);
  unsigned*           m1    = (unsigned*)(ws + 0x5C0000);
  float*              sums  = (float*)(ws + 0x5E0000);
  unsigned*           flist = (unsigned*)(ws + 0x5E1000);
  unsigned*           flist2= (unsigned*)(ws + 0x621000);
  float*              ev    = (float*)(ws + 0x140000);   // overlay
  float* out = (float*)d_out;

  hipMemsetAsync(cnt, 0, 0x100000, stream);   // zero histograms (graph-capturable)
  prep2_kernel<<<dim3(BN/256), 256, 0, stream>>>(preds, gts, A, G, cellA, cellG, cnt, sums);
  scan_kernel<<<dim3(8), 1024, 0, stream>>>(cnt, offs, fill);
  scatter_kernel<<<dim3(BN/256), 256, 0, stream>>>(A, G, cellA, cellG, fill, sA, iA, sG, iG);
  query_kernel<<<dim3(2048), 256, 0, stream>>>(sA, iA, sG, iG, offs, cnt, m2, m1, flist, sums);
  ring2_kernel<<<dim3(4096), 256, 0, stream>>>(sA, iA, sG, iG, offs, cnt, m2, m1, flist, sums, flist2);
  brute_kernel<<<dim3(2048), 256, 0, stream>>>(sA, iA, sG, iG, flist2, sums, m2, m1);
  edgeA_kernel<<<dim3(512), 256, 0, stream>>>(preds, normals, edges, m2, m1, ev, sums);
  edgeB_kernel<<<dim3(384), 256, 0, stream>>>(ev, sums, out);
}

// Round 20
// 74.195 us; speedup vs baseline: 3.5945x; 1.5471x over previous
//
#include <hip/hip_runtime.h>

namespace {

constexpr int B = 4;
constexpr int N = 8192;          // power of two (N = 1<<13)
constexpr int E = 24576;
constexpr int BN = B * N;
constexpr int BE = B * E;
constexpr int CHUNK = 256;       // staged points per wave-unit
constexpr int RT = 4;            // rows per thread -> 8192 units / 2048 blocks

typedef float f32x2 __attribute__((ext_vector_type(2)));

// Monotonic float <-> uint mapping (total order matches float compare)
__device__ __forceinline__ unsigned fkey(float f) {
  unsigned b = __float_as_uint(f);
  return b ^ ((b & 0x80000000u) ? 0xFFFFFFFFu : 0x80000000u);
}
__device__ __forceinline__ float funkey(unsigned k) {
  unsigned b = k ^ ((k & 0x80000000u) ? 0x80000000u : 0xFFFFFFFFu);
  return __uint_as_float(b);
}
// 3-input min in one instruction (T17)
__device__ __forceinline__ float min3f(float a, float b, float c) {
  float d;
  asm("v_min3_f32 %0, %1, %2, %3" : "=v"(d) : "v"(a), "v"(b), "v"(c));
  return d;
}
// packed 2xf32 fma with the staged (wave-uniform) operand in SGPRs
__device__ __forceinline__ f32x2 pk_fma_vsv(f32x2 a, f32x2 bs, f32x2 c) {
  f32x2 d;
  asm("v_pk_fma_f32 %0, %1, %2, %3" : "=v"(d) : "v"(a), "s"(bs), "v"(c));
  return d;
}
// packed 2xf32 fma, all-VGPR (argmin epilogue re-compute; same instruction &
// operand order as pk_fma_vsv -> bitwise identical result)
__device__ __forceinline__ f32x2 pk_fma_vvv(f32x2 a, f32x2 b, f32x2 c) {
  f32x2 d;
  asm("v_pk_fma_f32 %0, %1, %2, %3" : "=v"(d) : "v"(a), "v"(b), "v"(c));
  return d;
}

// sums layout (floats): [0]=s1, [1]=s2, [2]=cos sum, [3..14]=nsq[b][d],
// [15..26]=vsq[b][d]

// A[i] = (-2*p, |p|^2) etc; A2/G2 = pair-packed: for pair p (points 2p,2p+1):
//   float4[2p]   = (x_{2p}, x_{2p+1}, y_{2p}, y_{2p+1})
//   float4[2p+1] = (z_{2p}, z_{2p+1}, w_{2p}, w_{2p+1})
__global__ __launch_bounds__(256) void prep_kernel(const float* __restrict__ preds,
                                                   const float* __restrict__ gts,
                                                   float4* __restrict__ A,
                                                   float4* __restrict__ G,
                                                   float* __restrict__ A2f,
                                                   float* __restrict__ G2f,
                                                   unsigned long long* __restrict__ m2,
                                                   unsigned* __restrict__ m1,
                                                   float* __restrict__ sums) {
  int i = blockIdx.x * 256 + threadIdx.x;
  float px = preds[3*i], py = preds[3*i+1], pz = preds[3*i+2];
  float gx = gts[3*i],   gy = gts[3*i+1],  gz = gts[3*i+2];
  float ax = -2.f*px, ay = -2.f*py, az = -2.f*pz, aw = px*px + py*py + pz*pz;
  float bx = -2.f*gx, by = -2.f*gy, bz = -2.f*gz, bw = gx*gx + gy*gy + gz*gz;
  A[i] = make_float4(ax, ay, az, aw);
  G[i] = make_float4(bx, by, bz, bw);
  int p8 = (i >> 1) * 8, l = i & 1;
  A2f[p8 + 0 + l] = ax; A2f[p8 + 2 + l] = ay; A2f[p8 + 4 + l] = az; A2f[p8 + 6 + l] = aw;
  G2f[p8 + 0 + l] = bx; G2f[p8 + 2 + l] = by; G2f[p8 + 4 + l] = bz; G2f[p8 + 6 + l] = bw;
  m2[i] = ~0ULL;
  m1[i] = 0xFFFFFFFFu;
  if (i < 32) sums[i] = 0.f;
}

// Barrier-free, LDS-free min pass (R12-proven). Each WAVE owns:
//   unit u: ck = u&31, rg = (u>>5)&31, b = (u>>10)&3, which = u>>12
//   which=0: rows = gts, staged = preds(A2) -> m2, EXACT inline argmin:
//     per record-pair track winner via (min3, v_cmp, v_cndmask); strict-decrease
//     keeps the FIRST winner; epilogue disambiguates the record's 2 points with
//     an identical pk re-compute (t.x<=t.y -> lower idx).
//   which=1: rows = preds, staged = gts(G2) -> m1 (min only).
// Staged records wave-uniform -> scalar s_load path; pk_fma takes the record
// as its one allowed SGPR operand.
__global__ __launch_bounds__(256) void pass_wave(const float4* __restrict__ A,
                                                 const float4* __restrict__ G,
                                                 const float4* __restrict__ A2,
                                                 const float4* __restrict__ G2,
                                                 unsigned long long* __restrict__ m2,
                                                 unsigned* __restrict__ m1) {
  const int wid  = __builtin_amdgcn_readfirstlane((int)(threadIdx.x >> 6));
  const int lane = threadIdx.x & 63;
  const int u    = blockIdx.x * 4 + wid;
  const int ck = u & 31, rg = (u >> 5) & 31, b = (u >> 10) & 3, which = u >> 12;
  const float4* __restrict__ R  = which ? A  : G;
  const float4* __restrict__ S2 = which ? G2 : A2;
  const float4* __restrict__ Sg = S2 + b * N + ck * CHUNK;  // uniform base
  const int base = ck * CHUNK;
  f32x2 x2[RT], y2[RT], z2[RT];
  float w[RT], best[RT];
#pragma unroll
  for (int i = 0; i < RT; ++i) {
    float4 r = R[b * N + rg * (64 * RT) + i * 64 + lane];
    float xx = -0.5f * r.x, yy = -0.5f * r.y, zz = -0.5f * r.z;
    x2[i] = f32x2{xx, xx}; y2[i] = f32x2{yy, yy}; z2[i] = f32x2{zz, zz};
    w[i] = r.w; best[i] = 3.4e38f;
  }
  if (which == 0) {
    int wjj[RT];
#pragma unroll
    for (int i = 0; i < RT; ++i) wjj[i] = 0;
#pragma unroll 8
    for (int jr = 0; jr < CHUNK / 2; ++jr) {   // 128 record-pairs of 2 points
      float4 qa = Sg[2*jr], qb = Sg[2*jr + 1]; // uniform -> s_load path
      f32x2 qx = f32x2{qa.x, qa.y}, qy = f32x2{qa.z, qa.w};
      f32x2 qz = f32x2{qb.x, qb.y}, qw = f32x2{qb.z, qb.w};
#pragma unroll
      for (int i = 0; i < RT; ++i) {
        f32x2 t = pk_fma_vsv(z2[i], qz, qw);
        t = pk_fma_vsv(y2[i], qy, t);
        t = pk_fma_vsv(x2[i], qx, t);
        float m = min3f(best[i], t.x, t.y);
        wjj[i] = (m < best[i]) ? 2*jr : wjj[i];   // strict <: first winner kept
        best[i] = m;
      }
    }
#pragma unroll
    for (int i = 0; i < RT; ++i) {
      // disambiguate the 2 points of the winning record (per-lane gather)
      float4 qa = Sg[wjj[i]], qb = Sg[wjj[i] + 1];
      f32x2 t = pk_fma_vvv(z2[i], f32x2{qb.x, qb.y}, f32x2{qb.z, qb.w});
      t = pk_fma_vvv(y2[i], f32x2{qa.z, qa.w}, t);
      t = pk_fma_vvv(x2[i], f32x2{qa.x, qa.y}, t);
      const int idx = base + wjj[i] + ((t.x <= t.y) ? 0 : 1);  // tie -> lower idx
      const int gi = b * N + rg * (64 * RT) + i * 64 + lane;
      float d = w[i] + best[i];
      atomicMin(&m2[gi], ((unsigned long long)fkey(d) << 32) | (unsigned)idx);
    }
  } else {
#pragma unroll 8
    for (int jr = 0; jr < CHUNK / 2; ++jr) {
      float4 qa = Sg[2*jr], qb = Sg[2*jr + 1];
      f32x2 qx = f32x2{qa.x, qa.y}, qy = f32x2{qa.z, qa.w};
      f32x2 qz = f32x2{qb.x, qb.y}, qw = f32x2{qb.z, qb.w};
#pragma unroll
      for (int i = 0; i < RT; ++i) {
        f32x2 t = pk_fma_vsv(z2[i], qz, qw);
        t = pk_fma_vsv(y2[i], qy, t);
        t = pk_fma_vsv(x2[i], qx, t);
        best[i] = min3f(best[i], t.x, t.y);
      }
    }
#pragma unroll
    for (int i = 0; i < RT; ++i) {
      const int gi = b * N + rg * (64 * RT) + i * 64 + lane;
      atomicMin(&m1[gi], fkey(w[i] + best[i]));
    }
  }
}

__device__ __forceinline__ float block_sum(float v, float* ws) {
#pragma unroll
  for (int o = 32; o; o >>= 1) v += __shfl_down(v, o, 64);
  __syncthreads();
  if ((threadIdx.x & 63) == 0) ws[threadIdx.x >> 6] = v;
  __syncthreads();
  return ws[0] + ws[1] + ws[2] + ws[3];
}

// post: 128 blocks. nidx copy + chamfer reduce (R1-proven cheap tail).
__global__ __launch_bounds__(256) void post_kernel(const unsigned long long* __restrict__ m2,
                                                   const unsigned* __restrict__ m1,
                                                   unsigned* __restrict__ nidx,
                                                   float* __restrict__ sums) {
  __shared__ float ws[4];
  int i = blockIdx.x * 256 + threadIdx.x;
  unsigned long long p = m2[i];
  nidx[i] = (unsigned)p;
  float d2 = funkey((unsigned)(p >> 32));
  float d1 = funkey(m1[i]);
  float s2 = block_sum(d2, ws);
  float s1 = block_sum(d1, ws);
  if (threadIdx.x == 0) { atomicAdd(&sums[1], s2); atomicAdd(&sums[0], s1); }
}

// edge1: per-edge gathers once; store SoA (v,n) for edge2; all 6 column sums
// in ONE LDS round (2 barriers, 6 atomics per block).
__global__ __launch_bounds__(256) void edge1_kernel(const float* __restrict__ preds,
                                                    const float* __restrict__ normals,
                                                    const int* __restrict__ edges,
                                                    const unsigned* __restrict__ nidx,
                                                    float* __restrict__ ev,
                                                    float* __restrict__ sums) {
  __shared__ float ws[4][6];
  const int b = blockIdx.y;
  const int e = blockIdx.x * 256 + threadIdx.x;
  const int wid = threadIdx.x >> 6, lane = threadIdx.x & 63;
  int e0 = edges[2*e], e1 = edges[2*e+1];
  const float* pb = preds   + 3*(size_t)b*N;
  const float* nb = normals + 3*(size_t)b*N;
  float vx = pb[3*e0]   - pb[3*e1];
  float vy = pb[3*e0+1] - pb[3*e1+1];
  float vz = pb[3*e0+2] - pb[3*e1+2];
  unsigned ni = nidx[b*N + e0];
  float nx = nb[3*ni], ny = nb[3*ni+1], nz = nb[3*ni+2];
  const int be = b * E + e;
  ev[0*BE + be] = vx; ev[1*BE + be] = vy; ev[2*BE + be] = vz;
  ev[3*BE + be] = nx; ev[4*BE + be] = ny; ev[5*BE + be] = nz;
  float v[6] = {nx*nx, ny*ny, nz*nz, vx*vx, vy*vy, vz*vz};
#pragma unroll
  for (int k = 0; k < 6; ++k)
#pragma unroll
    for (int o = 32; o; o >>= 1) v[k] += __shfl_down(v[k], o, 64);
  if (lane == 0) {
#pragma unroll
    for (int k = 0; k < 6; ++k) ws[wid][k] = v[k];
  }
  __syncthreads();
  if (threadIdx.x < 6) {
    const int k = threadIdx.x;
    float t = ws[0][k] + ws[1][k] + ws[2][k] + ws[3][k];
    atomicAdd(&sums[(k < 3 ? 3 + k : 12 + k) + b*3], t);   // nsq: 3+b*3+d, vsq: 15+b*3+d
  }
}

// edge2: coalesced SoA reads, norms from sums (broadcast), 1 reduce, 1 atomic.
__global__ __launch_bounds__(256) void edge2_kernel(const float* __restrict__ ev,
                                                    float* __restrict__ sums) {
  __shared__ float ws[4];
  const int b = blockIdx.y;
  const int e = blockIdx.x * 256 + threadIdx.x;
  const int be = b * E + e;
  float vx = ev[0*BE + be], vy = ev[1*BE + be], vz = ev[2*BE + be];
  float nx = ev[3*BE + be], ny = ev[4*BE + be], nz = ev[5*BE + be];
  float inn0 = 1.f / fmaxf(sqrtf(sums[3  + b*3 + 0]), 1e-12f);
  float inn1 = 1.f / fmaxf(sqrtf(sums[3  + b*3 + 1]), 1e-12f);
  float inn2 = 1.f / fmaxf(sqrtf(sums[3  + b*3 + 2]), 1e-12f);
  float inv0 = 1.f / fmaxf(sqrtf(sums[15 + b*3 + 0]), 1e-12f);
  float inv1 = 1.f / fmaxf(sqrtf(sums[15 + b*3 + 1]), 1e-12f);
  float inv2 = 1.f / fmaxf(sqrtf(sums[15 + b*3 + 2]), 1e-12f);
  float c = fabsf(nx*inn0*vx*inv0 + ny*inn1*vy*inv1 + nz*inn2*vz*inv2);
#pragma unroll
  for (int o = 32; o; o >>= 1) c += __shfl_down(c, o, 64);
  if ((threadIdx.x & 63) == 0) ws[threadIdx.x >> 6] = c;
  __syncthreads();
  if (threadIdx.x == 0) atomicAdd(&sums[2], ws[0] + ws[1] + ws[2] + ws[3]);
}

__global__ void final_kernel(const float* __restrict__ sums, float* __restrict__ out) {
  if (threadIdx.x == 0 && blockIdx.x == 0) {
    float esum = 0.f;
#pragma unroll
    for (int i = 0; i < 12; ++i) esum += sums[15 + i];
    float chamfer   = (sums[0] + sums[1]) * (1.f / (float)BN);
    float edge_loss = esum * (1.f / (float)(B * E));
    float ncl       = sums[2] * (1.f / (float)(B * E));
    out[0] = 30000.f * chamfer + 240.f * edge_loss + 200000.f * ncl;
  }
}

} // namespace

extern "C" void kernel_launch(void* const* d_in, const int* in_sizes, int n_in,
                              void* d_out, int out_size, void* d_ws, size_t ws_size,
                              hipStream_t stream) {
  (void)in_sizes; (void)n_in; (void)out_size; (void)ws_size;
  const float* preds   = (const float*)d_in[0];
  const float* gts     = (const float*)d_in[1];
  const float* normals = (const float*)d_in[2];
  const int*   edges   = (const int*)d_in[3];
  char* ws = (char*)d_ws;
  // ws layout (16B aligned): A 512K | G 512K | A2 512K | G2 512K | m2 256K | m1 128K |
  //                          nidx 128K | sums 4K | ev 2.25M (6 x BE floats)
  float4*             A    = (float4*)(ws);
  float4*             G    = (float4*)(ws + 0x080000);
  float4*             A2   = (float4*)(ws + 0x100000);
  float4*             G2   = (float4*)(ws + 0x180000);
  unsigned long long* m2   = (unsigned long long*)(ws + 0x200000);
  unsigned*           m1   = (unsigned*)(ws + 0x240000);
  unsigned*           nidx = (unsigned*)(ws + 0x260000);
  float*              sums = (float*)(ws + 0x280000);
  float*              ev   = (float*)(ws + 0x281000);
  float* out = (float*)d_out;

  prep_kernel<<<dim3(BN/256), 256, 0, stream>>>(preds, gts, A, G, (float*)A2, (float*)G2,
                                                m2, m1, sums);
  // 8192 wave-units (2 passes x 4 b x 32 rowgroups x 32 chunks), 4 waves/block
  pass_wave<<<dim3(2048), 256, 0, stream>>>(A, G, A2, G2, m2, m1);
  // nidx copy + chamfer reduce (128 blocks)
  post_kernel<<<dim3(BN/256), 256, 0, stream>>>(m2, m1, nidx, sums);
  edge1_kernel<<<dim3(E/256, B), 256, 0, stream>>>(preds, normals, edges, nidx, ev, sums);
  edge2_kernel<<<dim3(E/256, B), 256, 0, stream>>>(ev, sums);
  final_kernel<<<1, 64, 0, stream>>>(sums, out);
}